// Round 1
// baseline (1381.012 us; speedup 1.0000x reference)
//
#include <hip/hip_runtime.h>

// ---------------------------------------------------------------------------
// GCN 3-layer forward on MI355X.
// Pipeline: deg -> dinv -> edge norm -> [GEMM -> selfloop-init -> edge
// scatter-atomicAdd] x3, bias+ReLU fused into next GEMM's input load,
// final kernel fuses b3 + mean pooling.
// ---------------------------------------------------------------------------

__global__ void init_deg_kernel(float* __restrict__ deg, int N) {
    int i = blockIdx.x * blockDim.x + threadIdx.x;
    if (i < N) deg[i] = 1.0f;  // self-loop weight
}

__global__ void deg_accum_kernel(const int* __restrict__ dst,
                                 const float* __restrict__ ew,
                                 float* __restrict__ deg, int E) {
    int e = blockIdx.x * blockDim.x + threadIdx.x;
    if (e < E) atomicAdd(&deg[dst[e]], ew[e]);
}

__global__ void dinv_kernel(float* __restrict__ deg, int N) {
    int i = blockIdx.x * blockDim.x + threadIdx.x;
    if (i < N) {
        float d = deg[i];
        deg[i] = d > 0.0f ? rsqrtf(d) : 0.0f;  // in-place: deg becomes dinv
    }
}

__global__ void norm_kernel(const int* __restrict__ src,
                            const int* __restrict__ dst,
                            const float* __restrict__ ew,
                            const float* __restrict__ dinv,
                            float* __restrict__ norm, int E) {
    int e = blockIdx.x * blockDim.x + threadIdx.x;
    if (e < E) norm[e] = dinv[src[e]] * ew[e] * dinv[dst[e]];
}

// out[n][o] = sum_k f(in[n][k]) * W[k][o],  f = optional (+bias_in[k], relu)
// W staged fully in LDS; 16 nodes per block, 256 threads.
template <int K, int M, bool RELU, bool BIAS>
__global__ __launch_bounds__(256) void gemm_kernel(
    const float* __restrict__ in, const float* __restrict__ W,
    const float* __restrict__ bias_in, float* __restrict__ out, int N) {
    constexpr int NPB = 16;  // nodes per block
    __shared__ float Wl[K * M];
    __shared__ float xl[NPB * K];
    const int tid = threadIdx.x;
    const int node0 = blockIdx.x * NPB;

    for (int i = tid; i < K * M; i += 256) Wl[i] = W[i];
    for (int i = tid; i < NPB * K; i += 256) {
        int ln = i / K, k = i % K;
        int node = node0 + ln;
        float v = 0.0f;
        if (node < N) {
            v = in[node * K + k];
            if (BIAS) v += bias_in[k];
            if (RELU) v = fmaxf(v, 0.0f);
        }
        xl[i] = v;
    }
    __syncthreads();

    constexpr int GROUPS = 256 / M;   // 4 (M=64) or 8 (M=32)
    constexpr int NPG = NPB / GROUPS; // nodes per group
    const int o = tid % M;
    const int g = tid / M;
    for (int j = 0; j < NPG; ++j) {
        int ln = g * NPG + j;
        float acc = 0.0f;
#pragma unroll 8
        for (int k = 0; k < K; ++k) acc += xl[ln * K + k] * Wl[k * M + o];
        int node = node0 + ln;
        if (node < N) out[node * M + o] = acc;
    }
}

// agg[i][f] = h[i][f] * dinv[i]^2   (self-loop contribution, initializes agg)
template <int M>
__global__ void selfloop_kernel(const float* __restrict__ h,
                                const float* __restrict__ dinv,
                                float* __restrict__ agg, int N) {
    int t = blockIdx.x * blockDim.x + threadIdx.x;
    if (t < N * M) {
        int i = t / M;
        float di = dinv[i];
        agg[t] = h[t] * di * di;
    }
}

// agg[dst[e]][f] += h[src[e]][f] * norm[e]   one thread per (edge, feature)
template <int M>
__global__ void aggregate_kernel(const float* __restrict__ h,
                                 const int* __restrict__ src,
                                 const int* __restrict__ dst,
                                 const float* __restrict__ norm,
                                 float* __restrict__ agg, int E) {
    int t = blockIdx.x * blockDim.x + threadIdx.x;
    int e = t / M;
    int f = t % M;
    if (e < E) {
        int s = src[e];
        int d = dst[e];
        float v = h[s * M + f] * norm[e];
        atomicAdd(&agg[d * M + f], v);
    }
}

// out[t] += b3[f]; accumulate per-feature sums for mean pooling
__global__ void final_kernel(float* __restrict__ out,
                             const float* __restrict__ b3,
                             float* __restrict__ mean_acc, int N) {
    __shared__ float ssum[32];
    int t = blockIdx.x * blockDim.x + threadIdx.x;
    if (threadIdx.x < 32) ssum[threadIdx.x] = 0.0f;
    __syncthreads();
    int f = threadIdx.x & 31;
    float v = 0.0f;
    if (t < N * 32) {
        v = out[t] + b3[f];
        out[t] = v;
    }
    // wave(64) covers 2 nodes x 32 feats: fold upper half onto lower
    v += __shfl_down(v, 32);
    if ((threadIdx.x & 63) < 32) atomicAdd(&ssum[f], v);
    __syncthreads();
    if (threadIdx.x < 32) atomicAdd(&mean_acc[threadIdx.x], ssum[threadIdx.x]);
}

__global__ void write_mean_kernel(const float* __restrict__ mean_acc,
                                  float* __restrict__ out_tail, float invN) {
    int f = threadIdx.x;
    if (f < 32) out_tail[f] = mean_acc[f] * invN;
}

extern "C" void kernel_launch(void* const* d_in, const int* in_sizes, int n_in,
                              void* d_out, int out_size, void* d_ws,
                              size_t ws_size, hipStream_t stream) {
    const float* x  = (const float*)d_in[0];
    const int*   ei = (const int*)d_in[1];
    const float* ew = (const float*)d_in[2];
    const float* W1 = (const float*)d_in[3];
    const float* b1 = (const float*)d_in[4];
    const float* W2 = (const float*)d_in[5];
    const float* b2 = (const float*)d_in[6];
    const float* W3 = (const float*)d_in[7];
    const float* b3 = (const float*)d_in[8];

    const int N = in_sizes[0] / 128;
    const int E = in_sizes[1] / 2;
    const int* src = ei;
    const int* dst = ei + E;

    float* out = (float*)d_out;
    float* ws = (float*)d_ws;
    // workspace layout (floats): deg/dinv [N] | norm [E] | bufA [N*64] | bufB [N*64] | mean [32]
    float* deg  = ws;
    float* norm = deg + N;
    float* bufA = norm + E;
    float* bufB = bufA + (size_t)N * 64;
    float* mean = bufB + (size_t)N * 64;

    hipMemsetAsync(mean, 0, 32 * sizeof(float), stream);

    init_deg_kernel<<<(N + 255) / 256, 256, 0, stream>>>(deg, N);
    deg_accum_kernel<<<(E + 255) / 256, 256, 0, stream>>>(dst, ew, deg, E);
    dinv_kernel<<<(N + 255) / 256, 256, 0, stream>>>(deg, N);
    norm_kernel<<<(E + 255) / 256, 256, 0, stream>>>(src, dst, ew, deg, norm, E);

    // ---- layer 1: h1 = x @ W1 ; agg1 = A_norm @ h1 ----
    gemm_kernel<128, 64, false, false>
        <<<(N + 15) / 16, 256, 0, stream>>>(x, W1, nullptr, bufA, N);
    selfloop_kernel<64>
        <<<(N * 64 + 255) / 256, 256, 0, stream>>>(bufA, deg, bufB, N);
    aggregate_kernel<64>
        <<<(E * 64 + 255) / 256, 256, 0, stream>>>(bufA, src, dst, norm, bufB, E);

    // ---- layer 2: h2 = relu(agg1 + b1) @ W2 ; agg2 = A_norm @ h2 ----
    gemm_kernel<64, 64, true, true>
        <<<(N + 15) / 16, 256, 0, stream>>>(bufB, W2, b1, bufA, N);
    selfloop_kernel<64>
        <<<(N * 64 + 255) / 256, 256, 0, stream>>>(bufA, deg, bufB, N);
    aggregate_kernel<64>
        <<<(E * 64 + 255) / 256, 256, 0, stream>>>(bufA, src, dst, norm, bufB, E);

    // ---- layer 3: h3 = relu(agg2 + b2) @ W3 ; agg3 = A_norm @ h3 (into d_out) ----
    gemm_kernel<64, 32, true, true>
        <<<(N + 15) / 16, 256, 0, stream>>>(bufB, W3, b2, bufA, N);
    selfloop_kernel<32>
        <<<(N * 32 + 255) / 256, 256, 0, stream>>>(bufA, deg, out, N);
    aggregate_kernel<32>
        <<<(E * 32 + 255) / 256, 256, 0, stream>>>(bufA, src, dst, norm, out, E);

    // ---- epilogue: + b3, mean pool ----
    final_kernel<<<(N * 32 + 255) / 256, 256, 0, stream>>>(out, b3, mean, N);
    write_mean_kernel<<<1, 32, 0, stream>>>(mean, out + (size_t)N * 32,
                                            1.0f / (float)N);
}

// Round 2
// 1156.189 us; speedup vs baseline: 1.1945x; 1.1945x over previous
//
#include <hip/hip_runtime.h>

// ---------------------------------------------------------------------------
// GCN 3-layer forward on MI355X — CSR-by-dst gather version.
// Per call: deg -> dinv -> histogram -> 2-level exclusive scan -> scatter
// edges (src,norm packed 8B) sorted by dst. Then per layer:
//   GEMM (bias+relu of previous layer fused on input load)
//   CSR aggregate: one wave per dst node, lane=feature, single write,
//   self-loop fused; layer 3 also fuses +b3 and mean pooling.
// ---------------------------------------------------------------------------

__global__ void init_kernel(float* __restrict__ deg, int* __restrict__ cnt,
                            int N) {
    int i = blockIdx.x * blockDim.x + threadIdx.x;
    if (i < N) { deg[i] = 1.0f; cnt[i] = 0; }
}

__global__ void deg_hist_kernel(const int* __restrict__ dst,
                                const float* __restrict__ ew,
                                float* __restrict__ deg, int* __restrict__ cnt,
                                int E) {
    int e = blockIdx.x * blockDim.x + threadIdx.x;
    if (e < E) {
        int d = dst[e];
        atomicAdd(&deg[d], ew[e]);
        atomicAdd(&cnt[d], 1);
    }
}

__global__ void dinv_kernel(float* __restrict__ deg, int N) {
    int i = blockIdx.x * blockDim.x + threadIdx.x;
    if (i < N) {
        float d = deg[i];
        deg[i] = d > 0.0f ? rsqrtf(d) : 0.0f;  // in-place: deg -> dinv
    }
}

// ---- 2-level exclusive scan over cnt[N] -> offs[N+1] ----
__global__ void scan_block_kernel(const int* __restrict__ cnt,
                                  int* __restrict__ offs,
                                  int* __restrict__ partials, int N) {
    __shared__ int s[256];
    int i = blockIdx.x * 256 + threadIdx.x;
    int v = (i < N) ? cnt[i] : 0;
    s[threadIdx.x] = v;
    __syncthreads();
    for (int off = 1; off < 256; off <<= 1) {
        int t = (threadIdx.x >= off) ? s[threadIdx.x - off] : 0;
        __syncthreads();
        s[threadIdx.x] += t;
        __syncthreads();
    }
    if (i < N) offs[i] = s[threadIdx.x] - v;  // exclusive
    if (threadIdx.x == 255) partials[blockIdx.x] = s[255];
}

__global__ void scan_partials_kernel(int* __restrict__ partials, int P) {
    __shared__ int s[512];
    int v = (threadIdx.x < P) ? partials[threadIdx.x] : 0;
    s[threadIdx.x] = v;
    __syncthreads();
    for (int off = 1; off < 512; off <<= 1) {
        int t = (threadIdx.x >= off) ? s[threadIdx.x - off] : 0;
        __syncthreads();
        s[threadIdx.x] += t;
        __syncthreads();
    }
    if (threadIdx.x < P) partials[threadIdx.x] = s[threadIdx.x] - v;  // excl
}

__global__ void add_offsets_kernel(int* __restrict__ offs,
                                   const int* __restrict__ partials,
                                   int* __restrict__ cursor, int N, int E) {
    int i = blockIdx.x * 256 + threadIdx.x;
    if (i < N) {
        int o = offs[i] + partials[blockIdx.x];
        offs[i] = o;
        cursor[i] = o;
    }
    if (i == N - 1) offs[N] = E;
}

// scatter edges into CSR order by dst; fuse norm computation
__global__ void scatter_edges_kernel(const int* __restrict__ src,
                                     const int* __restrict__ dst,
                                     const float* __restrict__ ew,
                                     const float* __restrict__ dinv,
                                     int* __restrict__ cursor,
                                     int2* __restrict__ edges, int E) {
    int e = blockIdx.x * blockDim.x + threadIdx.x;
    if (e < E) {
        int s = src[e], d = dst[e];
        float nrm = dinv[s] * ew[e] * dinv[d];
        int pos = atomicAdd(&cursor[d], 1);
        edges[pos] = make_int2(s, __float_as_int(nrm));
    }
}

// out[n][o] = sum_k f(in[n][k]) * W[k][o],  f = optional (+bias_in[k], relu)
template <int K, int M, bool RELU, bool BIAS>
__global__ __launch_bounds__(256) void gemm_kernel(
    const float* __restrict__ in, const float* __restrict__ W,
    const float* __restrict__ bias_in, float* __restrict__ out, int N) {
    constexpr int NPB = 16;  // nodes per block
    __shared__ float Wl[K * M];
    __shared__ float xl[NPB * K];
    const int tid = threadIdx.x;
    const int node0 = blockIdx.x * NPB;

    for (int i = tid; i < K * M; i += 256) Wl[i] = W[i];
    for (int i = tid; i < NPB * K; i += 256) {
        int ln = i / K, k = i % K;
        int node = node0 + ln;
        float v = 0.0f;
        if (node < N) {
            v = in[(size_t)node * K + k];
            if (BIAS) v += bias_in[k];
            if (RELU) v = fmaxf(v, 0.0f);
        }
        xl[i] = v;
    }
    __syncthreads();

    constexpr int GROUPS = 256 / M;
    constexpr int NPG = NPB / GROUPS;
    const int o = tid % M;
    const int g = tid / M;
    for (int j = 0; j < NPG; ++j) {
        int ln = g * NPG + j;
        float acc = 0.0f;
#pragma unroll 8
        for (int k = 0; k < K; ++k) acc += xl[ln * K + k] * Wl[k * M + o];
        int node = node0 + ln;
        if (node < N) out[(size_t)node * M + o] = acc;
    }
}

// CSR aggregate, M=64: one wave per node, lane = feature. Self-loop fused.
__global__ __launch_bounds__(256) void agg64_kernel(
    const float* __restrict__ h, const int2* __restrict__ edges,
    const int* __restrict__ offs, const float* __restrict__ dinv,
    float* __restrict__ out, int N) {
    int wave = threadIdx.x >> 6, lane = threadIdx.x & 63;
    int node = blockIdx.x * 4 + wave;
    if (node >= N) return;
    int j = offs[node], end = offs[node + 1];
    float acc = 0.0f;
    for (; j + 1 < end; j += 2) {  // unroll x2 for 2 outstanding row loads
        int2 e0 = edges[j];
        int2 e1 = edges[j + 1];
        float v0 = h[(size_t)e0.x * 64 + lane];
        float v1 = h[(size_t)e1.x * 64 + lane];
        acc += v0 * __int_as_float(e0.y) + v1 * __int_as_float(e1.y);
    }
    if (j < end) {
        int2 e0 = edges[j];
        acc += h[(size_t)e0.x * 64 + lane] * __int_as_float(e0.y);
    }
    float di = dinv[node];
    out[(size_t)node * 64 + lane] = acc + h[(size_t)node * 64 + lane] * di * di;
}

// CSR aggregate, M=32, final layer: fold wave halves over alternating edges,
// fuse +b3, write d_out, accumulate mean-pool sums.
__global__ __launch_bounds__(256) void agg32_final_kernel(
    const float* __restrict__ h, const int2* __restrict__ edges,
    const int* __restrict__ offs, const float* __restrict__ dinv,
    const float* __restrict__ b3, float* __restrict__ out,
    float* __restrict__ mean_acc, int N) {
    __shared__ float ssum[32];
    if (threadIdx.x < 32) ssum[threadIdx.x] = 0.0f;
    __syncthreads();
    int wave = threadIdx.x >> 6, lane = threadIdx.x & 63;
    int node = blockIdx.x * 4 + wave;
    int f = lane & 31, half = lane >> 5;
    float acc = 0.0f;
    if (node < N) {
        int start = offs[node], end = offs[node + 1];
        for (int j = start + half; j < end; j += 2) {
            int2 e0 = edges[j];
            acc += h[(size_t)e0.x * 32 + f] * __int_as_float(e0.y);
        }
    }
    acc += __shfl_down(acc, 32);  // fold upper-half partials onto lanes 0..31
    float v = 0.0f;
    if (node < N && half == 0) {
        float di = dinv[node];
        v = acc + h[(size_t)node * 32 + f] * di * di + b3[f];
        out[(size_t)node * 32 + f] = v;
    }
    if (half == 0) atomicAdd(&ssum[f], v);
    __syncthreads();
    if (threadIdx.x < 32) atomicAdd(&mean_acc[threadIdx.x], ssum[threadIdx.x]);
}

__global__ void write_mean_kernel(const float* __restrict__ mean_acc,
                                  float* __restrict__ out_tail, float invN) {
    int f = threadIdx.x;
    if (f < 32) out_tail[f] = mean_acc[f] * invN;
}

extern "C" void kernel_launch(void* const* d_in, const int* in_sizes, int n_in,
                              void* d_out, int out_size, void* d_ws,
                              size_t ws_size, hipStream_t stream) {
    const float* x  = (const float*)d_in[0];
    const int*   ei = (const int*)d_in[1];
    const float* ew = (const float*)d_in[2];
    const float* W1 = (const float*)d_in[3];
    const float* b1 = (const float*)d_in[4];
    const float* W2 = (const float*)d_in[5];
    const float* b2 = (const float*)d_in[6];
    const float* W3 = (const float*)d_in[7];
    const float* b3 = (const float*)d_in[8];

    const int N = in_sizes[0] / 128;
    const int E = in_sizes[1] / 2;
    const int* src = ei;
    const int* dst = ei + E;

    float* out = (float*)d_out;
    char* ws = (char*)d_ws;
    // workspace carve (4B units)
    float* deg     = (float*)ws;                    ws += (size_t)N * 4;
    int*   cnt     = (int*)ws;                      ws += (size_t)N * 4;
    int*   offs    = (int*)ws;                      ws += (size_t)(N + 1) * 4;
    int*   partials= (int*)ws;                      ws += 512 * 4;
    int*   cursor  = (int*)ws;                      ws += (size_t)N * 4;
    int2*  edges   = (int2*)ws;                     ws += (size_t)E * 8;
    float* bufA    = (float*)ws;                    ws += (size_t)N * 64 * 4;
    float* bufB    = (float*)ws;                    ws += (size_t)N * 64 * 4;
    float* mean    = (float*)ws;                    ws += 32 * 4;

    const int nb_n = (N + 255) / 256;   // blocks over nodes
    const int nb_e = (E + 255) / 256;   // blocks over edges
    const int nb_a = (N + 3) / 4;       // aggregation: 4 nodes/block

    hipMemsetAsync(mean, 0, 32 * sizeof(float), stream);

    // ---- preprocessing: deg/dinv + CSR build (norm fused into scatter) ----
    init_kernel<<<nb_n, 256, 0, stream>>>(deg, cnt, N);
    deg_hist_kernel<<<nb_e, 256, 0, stream>>>(dst, ew, deg, cnt, E);
    dinv_kernel<<<nb_n, 256, 0, stream>>>(deg, N);
    scan_block_kernel<<<nb_n, 256, 0, stream>>>(cnt, offs, partials, N);
    scan_partials_kernel<<<1, 512, 0, stream>>>(partials, nb_n);
    add_offsets_kernel<<<nb_n, 256, 0, stream>>>(offs, partials, cursor, N, E);
    scatter_edges_kernel<<<nb_e, 256, 0, stream>>>(src, dst, ew, deg, cursor,
                                                   edges, E);

    // ---- layer 1 ----
    gemm_kernel<128, 64, false, false>
        <<<(N + 15) / 16, 256, 0, stream>>>(x, W1, nullptr, bufA, N);
    agg64_kernel<<<nb_a, 256, 0, stream>>>(bufA, edges, offs, deg, bufB, N);

    // ---- layer 2 ----
    gemm_kernel<64, 64, true, true>
        <<<(N + 15) / 16, 256, 0, stream>>>(bufB, W2, b1, bufA, N);
    agg64_kernel<<<nb_a, 256, 0, stream>>>(bufA, edges, offs, deg, bufB, N);

    // ---- layer 3 ----
    gemm_kernel<64, 32, true, true>
        <<<(N + 15) / 16, 256, 0, stream>>>(bufB, W3, b2, bufA, N);
    agg32_final_kernel<<<nb_a, 256, 0, stream>>>(bufA, edges, offs, deg, b3,
                                                 out, mean, N);

    // ---- epilogue: mean pool ----
    write_mean_kernel<<<1, 32, 0, stream>>>(mean, out + (size_t)N * 32,
                                            1.0f / (float)N);
}

// Round 3
// 887.100 us; speedup vs baseline: 1.5568x; 1.3033x over previous
//
#include <hip/hip_runtime.h>

// ---------------------------------------------------------------------------
// GCN 3-layer forward on MI355X — CSR gather + high-MLP aggregation.
// Aggregation: wave per node, edge-slots x float4 feature lanes, unroll x2
// => 8 (64-wide) / 16 (32-wide) independent row loads in flight per wave.
// GEMM: k-blocked x4, float4 LDS reads, W reused across NPG nodes.
// ---------------------------------------------------------------------------

__global__ void init_kernel(float* __restrict__ deg, int* __restrict__ cnt,
                            int N) {
    int i = blockIdx.x * blockDim.x + threadIdx.x;
    if (i < N) { deg[i] = 1.0f; cnt[i] = 0; }
}

__global__ void deg_hist_kernel(const int* __restrict__ dst,
                                const float* __restrict__ ew,
                                float* __restrict__ deg, int* __restrict__ cnt,
                                int E) {
    int e = blockIdx.x * blockDim.x + threadIdx.x;
    if (e < E) {
        int d = dst[e];
        atomicAdd(&deg[d], ew[e]);
        atomicAdd(&cnt[d], 1);
    }
}

__global__ void dinv_kernel(float* __restrict__ deg, int N) {
    int i = blockIdx.x * blockDim.x + threadIdx.x;
    if (i < N) {
        float d = deg[i];
        deg[i] = d > 0.0f ? rsqrtf(d) : 0.0f;  // in-place: deg -> dinv
    }
}

// ---- 2-level exclusive scan over cnt[N] -> offs[N+1] ----
__global__ void scan_block_kernel(const int* __restrict__ cnt,
                                  int* __restrict__ offs,
                                  int* __restrict__ partials, int N) {
    __shared__ int s[256];
    int i = blockIdx.x * 256 + threadIdx.x;
    int v = (i < N) ? cnt[i] : 0;
    s[threadIdx.x] = v;
    __syncthreads();
    for (int off = 1; off < 256; off <<= 1) {
        int t = (threadIdx.x >= off) ? s[threadIdx.x - off] : 0;
        __syncthreads();
        s[threadIdx.x] += t;
        __syncthreads();
    }
    if (i < N) offs[i] = s[threadIdx.x] - v;  // exclusive
    if (threadIdx.x == 255) partials[blockIdx.x] = s[255];
}

__global__ void scan_partials_kernel(int* __restrict__ partials, int P) {
    __shared__ int s[512];
    int v = (threadIdx.x < P) ? partials[threadIdx.x] : 0;
    s[threadIdx.x] = v;
    __syncthreads();
    for (int off = 1; off < 512; off <<= 1) {
        int t = (threadIdx.x >= off) ? s[threadIdx.x - off] : 0;
        __syncthreads();
        s[threadIdx.x] += t;
        __syncthreads();
    }
    if (threadIdx.x < P) partials[threadIdx.x] = s[threadIdx.x] - v;  // excl
}

__global__ void add_offsets_kernel(int* __restrict__ offs,
                                   const int* __restrict__ partials,
                                   int* __restrict__ cursor, int N, int E) {
    int i = blockIdx.x * 256 + threadIdx.x;
    if (i < N) {
        int o = offs[i] + partials[blockIdx.x];
        offs[i] = o;
        cursor[i] = o;
    }
    if (i == N - 1) offs[N] = E;
}

// scatter edges into CSR order by dst; fuse norm computation
__global__ void scatter_edges_kernel(const int* __restrict__ src,
                                     const int* __restrict__ dst,
                                     const float* __restrict__ ew,
                                     const float* __restrict__ dinv,
                                     int* __restrict__ cursor,
                                     int2* __restrict__ edges, int E) {
    int e = blockIdx.x * blockDim.x + threadIdx.x;
    if (e < E) {
        int s = src[e], d = dst[e];
        float nrm = dinv[s] * ew[e] * dinv[d];
        int pos = atomicAdd(&cursor[d], 1);
        edges[pos] = make_int2(s, __float_as_int(nrm));
    }
}

// out[n][o] = sum_k f(in[n][k]) * W[k][o],  f = optional (+bias_in[k], relu)
// k-blocked x4, float4 LDS reads, W element reused across NPG nodes.
template <int K, int M, bool RELU, bool BIAS>
__global__ __launch_bounds__(256) void gemm_kernel(
    const float* __restrict__ in, const float* __restrict__ W,
    const float* __restrict__ bias_in, float* __restrict__ out, int N) {
    constexpr int NPB = 16;  // nodes per block
    __shared__ __align__(16) float Wl[K * M];
    __shared__ __align__(16) float xl[NPB * K];
    const int tid = threadIdx.x;
    const int node0 = blockIdx.x * NPB;

    for (int i = tid; i < K * M / 4; i += 256)
        ((float4*)Wl)[i] = ((const float4*)W)[i];
    for (int i = tid; i < NPB * K / 4; i += 256) {
        int ln = i / (K / 4), kq = i % (K / 4);
        int node = node0 + ln;
        float4 v = make_float4(0.f, 0.f, 0.f, 0.f);
        if (node < N) {
            v = ((const float4*)in)[(size_t)node * (K / 4) + kq];
            if (BIAS) {
                float4 b = ((const float4*)bias_in)[kq];
                v.x += b.x; v.y += b.y; v.z += b.z; v.w += b.w;
            }
            if (RELU) {
                v.x = fmaxf(v.x, 0.f); v.y = fmaxf(v.y, 0.f);
                v.z = fmaxf(v.z, 0.f); v.w = fmaxf(v.w, 0.f);
            }
        }
        ((float4*)xl)[i] = v;
    }
    __syncthreads();

    constexpr int GROUPS = 256 / M;   // 4 (M=64) or 8 (M=32)
    constexpr int NPG = NPB / GROUPS; // 4 or 2 nodes per thread
    const int o = tid % M;
    const int g = tid / M;
    const float4* xl4 = (const float4*)xl;
    float acc[NPG] = {};
#pragma unroll 4
    for (int k = 0; k < K; k += 4) {
        float w0 = Wl[k * M + o];
        float w1 = Wl[(k + 1) * M + o];
        float w2 = Wl[(k + 2) * M + o];
        float w3 = Wl[(k + 3) * M + o];
#pragma unroll
        for (int jj = 0; jj < NPG; ++jj) {
            float4 xv = xl4[(g * NPG + jj) * (K / 4) + (k >> 2)];
            acc[jj] += xv.x * w0 + xv.y * w1 + xv.z * w2 + xv.w * w3;
        }
    }
#pragma unroll
    for (int jj = 0; jj < NPG; ++jj) {
        int node = node0 + g * NPG + jj;
        if (node < N) out[(size_t)node * M + o] = acc[jj];
    }
}

// CSR aggregate, M=64: wave per node. 4 edge-slots x 16 float4-lanes,
// unroll x2 => 8 rows in flight. Self-loop fused.
__global__ __launch_bounds__(256) void agg64_kernel(
    const float* __restrict__ h, const int2* __restrict__ edges,
    const int* __restrict__ offs, const float* __restrict__ dinv,
    float* __restrict__ out, int N) {
    const int wave = threadIdx.x >> 6, lane = threadIdx.x & 63;
    const int node = blockIdx.x * 4 + wave;
    if (node >= N) return;
    const int slot = lane >> 4;  // 0..3
    const int q = lane & 15;     // float4 index: 16*4 = 64 floats
    const float4* __restrict__ h4 = (const float4*)h;
    const int start = offs[node], end = offs[node + 1];
    float4 acc = make_float4(0.f, 0.f, 0.f, 0.f);
    int j = start + slot;
    for (; j + 4 < end; j += 8) {
        int2 e0 = edges[j];
        int2 e1 = edges[j + 4];
        float4 v0 = h4[(size_t)e0.x * 16 + q];
        float4 v1 = h4[(size_t)e1.x * 16 + q];
        float n0 = __int_as_float(e0.y), n1 = __int_as_float(e1.y);
        acc.x += v0.x * n0 + v1.x * n1;
        acc.y += v0.y * n0 + v1.y * n1;
        acc.z += v0.z * n0 + v1.z * n1;
        acc.w += v0.w * n0 + v1.w * n1;
    }
    if (j < end) {
        int2 e0 = edges[j];
        float4 v0 = h4[(size_t)e0.x * 16 + q];
        float n0 = __int_as_float(e0.y);
        acc.x += v0.x * n0; acc.y += v0.y * n0;
        acc.z += v0.z * n0; acc.w += v0.w * n0;
    }
    // fold the 4 slots
    acc.x += __shfl_xor(acc.x, 16); acc.y += __shfl_xor(acc.y, 16);
    acc.z += __shfl_xor(acc.z, 16); acc.w += __shfl_xor(acc.w, 16);
    acc.x += __shfl_xor(acc.x, 32); acc.y += __shfl_xor(acc.y, 32);
    acc.z += __shfl_xor(acc.z, 32); acc.w += __shfl_xor(acc.w, 32);
    if (slot == 0) {
        float di = dinv[node];
        float sc = di * di;
        float4 hv = h4[(size_t)node * 16 + q];
        float4 o;
        o.x = acc.x + hv.x * sc; o.y = acc.y + hv.y * sc;
        o.z = acc.z + hv.z * sc; o.w = acc.w + hv.w * sc;
        ((float4*)out)[(size_t)node * 16 + q] = o;
    }
}

// CSR aggregate, M=32, final layer: 8 edge-slots x 8 float4-lanes, unroll x2
// => 16 rows in flight. Fuses +b3, d_out write, mean-pool accumulation.
__global__ __launch_bounds__(256) void agg32_final_kernel(
    const float* __restrict__ h, const int2* __restrict__ edges,
    const int* __restrict__ offs, const float* __restrict__ dinv,
    const float* __restrict__ b3, float* __restrict__ out,
    float* __restrict__ mean_acc, int N) {
    __shared__ float ssum[32];
    if (threadIdx.x < 32) ssum[threadIdx.x] = 0.0f;
    __syncthreads();
    const int wave = threadIdx.x >> 6, lane = threadIdx.x & 63;
    const int node = blockIdx.x * 4 + wave;
    const int slot = lane >> 3;  // 0..7
    const int q = lane & 7;      // float4 index: 8*4 = 32 floats
    const float4* __restrict__ h4 = (const float4*)h;
    float4 acc = make_float4(0.f, 0.f, 0.f, 0.f);
    if (node < N) {
        const int start = offs[node], end = offs[node + 1];
        int j = start + slot;
        for (; j + 8 < end; j += 16) {
            int2 e0 = edges[j];
            int2 e1 = edges[j + 8];
            float4 v0 = h4[(size_t)e0.x * 8 + q];
            float4 v1 = h4[(size_t)e1.x * 8 + q];
            float n0 = __int_as_float(e0.y), n1 = __int_as_float(e1.y);
            acc.x += v0.x * n0 + v1.x * n1;
            acc.y += v0.y * n0 + v1.y * n1;
            acc.z += v0.z * n0 + v1.z * n1;
            acc.w += v0.w * n0 + v1.w * n1;
        }
        if (j < end) {
            int2 e0 = edges[j];
            float4 v0 = h4[(size_t)e0.x * 8 + q];
            float n0 = __int_as_float(e0.y);
            acc.x += v0.x * n0; acc.y += v0.y * n0;
            acc.z += v0.z * n0; acc.w += v0.w * n0;
        }
    }
    // fold the 8 slots
    acc.x += __shfl_xor(acc.x, 8);  acc.y += __shfl_xor(acc.y, 8);
    acc.z += __shfl_xor(acc.z, 8);  acc.w += __shfl_xor(acc.w, 8);
    acc.x += __shfl_xor(acc.x, 16); acc.y += __shfl_xor(acc.y, 16);
    acc.z += __shfl_xor(acc.z, 16); acc.w += __shfl_xor(acc.w, 16);
    acc.x += __shfl_xor(acc.x, 32); acc.y += __shfl_xor(acc.y, 32);
    acc.z += __shfl_xor(acc.z, 32); acc.w += __shfl_xor(acc.w, 32);
    float4 o = make_float4(0.f, 0.f, 0.f, 0.f);
    if (node < N && slot == 0) {
        float di = dinv[node];
        float sc = di * di;
        float4 hv = h4[(size_t)node * 8 + q];
        float4 b = ((const float4*)b3)[q];
        o.x = acc.x + hv.x * sc + b.x;
        o.y = acc.y + hv.y * sc + b.y;
        o.z = acc.z + hv.z * sc + b.z;
        o.w = acc.w + hv.w * sc + b.w;
        ((float4*)out)[(size_t)node * 8 + q] = o;
    }
    if (slot == 0) {  // includes node>=N lanes with o = 0
        atomicAdd(&ssum[q * 4 + 0], o.x);
        atomicAdd(&ssum[q * 4 + 1], o.y);
        atomicAdd(&ssum[q * 4 + 2], o.z);
        atomicAdd(&ssum[q * 4 + 3], o.w);
    }
    __syncthreads();
    if (threadIdx.x < 32) atomicAdd(&mean_acc[threadIdx.x], ssum[threadIdx.x]);
}

__global__ void write_mean_kernel(const float* __restrict__ mean_acc,
                                  float* __restrict__ out_tail, float invN) {
    int f = threadIdx.x;
    if (f < 32) out_tail[f] = mean_acc[f] * invN;
}

extern "C" void kernel_launch(void* const* d_in, const int* in_sizes, int n_in,
                              void* d_out, int out_size, void* d_ws,
                              size_t ws_size, hipStream_t stream) {
    const float* x  = (const float*)d_in[0];
    const int*   ei = (const int*)d_in[1];
    const float* ew = (const float*)d_in[2];
    const float* W1 = (const float*)d_in[3];
    const float* b1 = (const float*)d_in[4];
    const float* W2 = (const float*)d_in[5];
    const float* b2 = (const float*)d_in[6];
    const float* W3 = (const float*)d_in[7];
    const float* b3 = (const float*)d_in[8];

    const int N = in_sizes[0] / 128;
    const int E = in_sizes[1] / 2;
    const int* src = ei;
    const int* dst = ei + E;

    float* out = (float*)d_out;
    char* wsp = (char*)d_ws;
    auto carve = [&](size_t bytes) {
        char* p = wsp;
        wsp += (bytes + 255) & ~(size_t)255;
        return p;
    };
    float* deg      = (float*)carve((size_t)N * 4);
    int*   cnt      = (int*)carve((size_t)N * 4);
    int*   offs     = (int*)carve((size_t)(N + 1) * 4);
    int*   partials = (int*)carve(512 * 4);
    int*   cursor   = (int*)carve((size_t)N * 4);
    int2*  edges    = (int2*)carve((size_t)E * 8);
    float* bufA     = (float*)carve((size_t)N * 64 * 4);
    float* bufB     = (float*)carve((size_t)N * 64 * 4);
    float* mean     = (float*)carve(32 * 4);

    const int nb_n = (N + 255) / 256;
    const int nb_e = (E + 255) / 256;
    const int nb_a = (N + 3) / 4;  // aggregation: 4 nodes (waves) per block

    hipMemsetAsync(mean, 0, 32 * sizeof(float), stream);

    // ---- preprocessing: deg/dinv + CSR build (norm fused into scatter) ----
    init_kernel<<<nb_n, 256, 0, stream>>>(deg, cnt, N);
    deg_hist_kernel<<<nb_e, 256, 0, stream>>>(dst, ew, deg, cnt, E);
    dinv_kernel<<<nb_n, 256, 0, stream>>>(deg, N);
    scan_block_kernel<<<nb_n, 256, 0, stream>>>(cnt, offs, partials, N);
    scan_partials_kernel<<<1, 512, 0, stream>>>(partials, nb_n);
    add_offsets_kernel<<<nb_n, 256, 0, stream>>>(offs, partials, cursor, N, E);
    scatter_edges_kernel<<<nb_e, 256, 0, stream>>>(src, dst, ew, deg, cursor,
                                                   edges, E);

    // ---- layer 1 ----
    gemm_kernel<128, 64, false, false>
        <<<(N + 15) / 16, 256, 0, stream>>>(x, W1, nullptr, bufA, N);
    agg64_kernel<<<nb_a, 256, 0, stream>>>(bufA, edges, offs, deg, bufB, N);

    // ---- layer 2 ----
    gemm_kernel<64, 64, true, true>
        <<<(N + 15) / 16, 256, 0, stream>>>(bufB, W2, b1, bufA, N);
    agg64_kernel<<<nb_a, 256, 0, stream>>>(bufA, edges, offs, deg, bufB, N);

    // ---- layer 3 ----
    gemm_kernel<64, 32, true, true>
        <<<(N + 15) / 16, 256, 0, stream>>>(bufB, W3, b2, bufA, N);
    agg32_final_kernel<<<nb_a, 256, 0, stream>>>(bufA, edges, offs, deg, b3,
                                                 out, mean, N);

    // ---- epilogue: mean pool ----
    write_mean_kernel<<<1, 32, 0, stream>>>(mean, out + (size_t)N * 32,
                                            1.0f / (float)N);
}

// Round 4
// 564.751 us; speedup vs baseline: 2.4453x; 1.5708x over previous
//
#include <hip/hip_runtime.h>

// ---------------------------------------------------------------------------
// GCN 3-layer forward on MI355X — CSR gather, bf16-staged activations.
// GEMM (fp32 accumulate) writes h as bf16 (RTN). Aggregation gathers bf16
// rows (half the bytes of fp32), accumulates fp32, writes fp32.
// Mean pooling uses 128 spread buckets to avoid same-address atomic
// serialization (Round-2 lesson: 25k blocks x 32 same-word atomics = 300us).
// ---------------------------------------------------------------------------

typedef unsigned int uint32;
typedef unsigned short ushort16;

__device__ __forceinline__ ushort f2bf(float v) {
    uint32 u = __float_as_uint(v);
    u += 0x7fff + ((u >> 16) & 1);  // round to nearest even
    return (ushort)(u >> 16);
}
__device__ __forceinline__ float bf_lo(uint32 u) {
    return __uint_as_float(u << 16);
}
__device__ __forceinline__ float bf_hi(uint32 u) {
    return __uint_as_float(u & 0xffff0000u);
}

__global__ void init_kernel(float* __restrict__ deg, int* __restrict__ cnt,
                            int N) {
    int i = blockIdx.x * blockDim.x + threadIdx.x;
    if (i < N) { deg[i] = 1.0f; cnt[i] = 0; }
}

__global__ void deg_hist_kernel(const int* __restrict__ dst,
                                const float* __restrict__ ew,
                                float* __restrict__ deg, int* __restrict__ cnt,
                                int E) {
    int e = blockIdx.x * blockDim.x + threadIdx.x;
    if (e < E) {
        int d = dst[e];
        atomicAdd(&deg[d], ew[e]);
        atomicAdd(&cnt[d], 1);
    }
}

__global__ void dinv_kernel(float* __restrict__ deg, int N) {
    int i = blockIdx.x * blockDim.x + threadIdx.x;
    if (i < N) {
        float d = deg[i];
        deg[i] = d > 0.0f ? rsqrtf(d) : 0.0f;  // in-place: deg -> dinv
    }
}

// ---- 2-level exclusive scan over cnt[N] -> offs[N+1] ----
__global__ void scan_block_kernel(const int* __restrict__ cnt,
                                  int* __restrict__ offs,
                                  int* __restrict__ partials, int N) {
    __shared__ int s[256];
    int i = blockIdx.x * 256 + threadIdx.x;
    int v = (i < N) ? cnt[i] : 0;
    s[threadIdx.x] = v;
    __syncthreads();
    for (int off = 1; off < 256; off <<= 1) {
        int t = (threadIdx.x >= off) ? s[threadIdx.x - off] : 0;
        __syncthreads();
        s[threadIdx.x] += t;
        __syncthreads();
    }
    if (i < N) offs[i] = s[threadIdx.x] - v;  // exclusive
    if (threadIdx.x == 255) partials[blockIdx.x] = s[255];
}

__global__ void scan_partials_kernel(int* __restrict__ partials, int P) {
    __shared__ int s[512];
    int v = (threadIdx.x < P) ? partials[threadIdx.x] : 0;
    s[threadIdx.x] = v;
    __syncthreads();
    for (int off = 1; off < 512; off <<= 1) {
        int t = (threadIdx.x >= off) ? s[threadIdx.x - off] : 0;
        __syncthreads();
        s[threadIdx.x] += t;
        __syncthreads();
    }
    if (threadIdx.x < P) partials[threadIdx.x] = s[threadIdx.x] - v;  // excl
}

__global__ void add_offsets_kernel(int* __restrict__ offs,
                                   const int* __restrict__ partials,
                                   int* __restrict__ cursor, int N, int E) {
    int i = blockIdx.x * 256 + threadIdx.x;
    if (i < N) {
        int o = offs[i] + partials[blockIdx.x];
        offs[i] = o;
        cursor[i] = o;
    }
    if (i == N - 1) offs[N] = E;
}

// scatter edges into CSR order by dst; fuse norm computation
__global__ void scatter_edges_kernel(const int* __restrict__ src,
                                     const int* __restrict__ dst,
                                     const float* __restrict__ ew,
                                     const float* __restrict__ dinv,
                                     int* __restrict__ cursor,
                                     int2* __restrict__ edges, int E) {
    int e = blockIdx.x * blockDim.x + threadIdx.x;
    if (e < E) {
        int s = src[e], d = dst[e];
        float nrm = dinv[s] * ew[e] * dinv[d];
        int pos = atomicAdd(&cursor[d], 1);
        edges[pos] = make_int2(s, __float_as_int(nrm));
    }
}

// out_bf16[n][o] = f(in[n]) @ W, f = optional (+bias_in, relu). fp32 math.
template <int K, int M, bool RELU, bool BIAS>
__global__ __launch_bounds__(256) void gemm_kernel(
    const float* __restrict__ in, const float* __restrict__ W,
    const float* __restrict__ bias_in, ushort* __restrict__ out, int N) {
    constexpr int NPB = 16;  // nodes per block
    __shared__ __align__(16) float Wl[K * M];
    __shared__ __align__(16) float xl[NPB * K];
    const int tid = threadIdx.x;
    const int node0 = blockIdx.x * NPB;

    for (int i = tid; i < K * M / 4; i += 256)
        ((float4*)Wl)[i] = ((const float4*)W)[i];
    for (int i = tid; i < NPB * K / 4; i += 256) {
        int ln = i / (K / 4), kq = i % (K / 4);
        int node = node0 + ln;
        float4 v = make_float4(0.f, 0.f, 0.f, 0.f);
        if (node < N) {
            v = ((const float4*)in)[(size_t)node * (K / 4) + kq];
            if (BIAS) {
                float4 b = ((const float4*)bias_in)[kq];
                v.x += b.x; v.y += b.y; v.z += b.z; v.w += b.w;
            }
            if (RELU) {
                v.x = fmaxf(v.x, 0.f); v.y = fmaxf(v.y, 0.f);
                v.z = fmaxf(v.z, 0.f); v.w = fmaxf(v.w, 0.f);
            }
        }
        ((float4*)xl)[i] = v;
    }
    __syncthreads();

    constexpr int GROUPS = 256 / M;
    constexpr int NPG = NPB / GROUPS;
    const int o = tid % M;
    const int g = tid / M;
    const float4* xl4 = (const float4*)xl;
    float acc[NPG] = {};
#pragma unroll 4
    for (int k = 0; k < K; k += 4) {
        float w0 = Wl[k * M + o];
        float w1 = Wl[(k + 1) * M + o];
        float w2 = Wl[(k + 2) * M + o];
        float w3 = Wl[(k + 3) * M + o];
#pragma unroll
        for (int jj = 0; jj < NPG; ++jj) {
            float4 xv = xl4[(g * NPG + jj) * (K / 4) + (k >> 2)];
            acc[jj] += xv.x * w0 + xv.y * w1 + xv.z * w2 + xv.w * w3;
        }
    }
#pragma unroll
    for (int jj = 0; jj < NPG; ++jj) {
        int node = node0 + g * NPG + jj;
        if (node < N) out[(size_t)node * M + o] = f2bf(acc[jj]);
    }
}

// CSR aggregate, 64-wide bf16 rows (128 B). Wave per node: 8 slots x 8 lanes
// (uint4 = 8 bf16), unroll x2 => 16 rows in flight. fp32 accumulate + out.
__global__ __launch_bounds__(256) void agg64_kernel(
    const ushort* __restrict__ h, const int2* __restrict__ edges,
    const int* __restrict__ offs, const float* __restrict__ dinv,
    float* __restrict__ out, int N) {
    const int wave = threadIdx.x >> 6, lane = threadIdx.x & 63;
    const int node = blockIdx.x * 4 + wave;
    if (node >= N) return;
    const int slot = lane >> 3;  // 0..7
    const int q = lane & 7;      // uint4 index within the 128 B row
    const uint4* __restrict__ h4 = (const uint4*)h;
    const int start = offs[node], end = offs[node + 1];
    float acc[8] = {};
    int j = start + slot;
    for (; j + 8 < end; j += 16) {
        int2 e0 = edges[j];
        int2 e1 = edges[j + 8];
        uint4 u0 = h4[(size_t)e0.x * 8 + q];
        uint4 u1 = h4[(size_t)e1.x * 8 + q];
        float n0 = __int_as_float(e0.y), n1 = __int_as_float(e1.y);
        acc[0] += bf_lo(u0.x) * n0 + bf_lo(u1.x) * n1;
        acc[1] += bf_hi(u0.x) * n0 + bf_hi(u1.x) * n1;
        acc[2] += bf_lo(u0.y) * n0 + bf_lo(u1.y) * n1;
        acc[3] += bf_hi(u0.y) * n0 + bf_hi(u1.y) * n1;
        acc[4] += bf_lo(u0.z) * n0 + bf_lo(u1.z) * n1;
        acc[5] += bf_hi(u0.z) * n0 + bf_hi(u1.z) * n1;
        acc[6] += bf_lo(u0.w) * n0 + bf_lo(u1.w) * n1;
        acc[7] += bf_hi(u0.w) * n0 + bf_hi(u1.w) * n1;
    }
    if (j < end) {
        int2 e0 = edges[j];
        uint4 u0 = h4[(size_t)e0.x * 8 + q];
        float n0 = __int_as_float(e0.y);
        acc[0] += bf_lo(u0.x) * n0; acc[1] += bf_hi(u0.x) * n0;
        acc[2] += bf_lo(u0.y) * n0; acc[3] += bf_hi(u0.y) * n0;
        acc[4] += bf_lo(u0.z) * n0; acc[5] += bf_hi(u0.z) * n0;
        acc[6] += bf_lo(u0.w) * n0; acc[7] += bf_hi(u0.w) * n0;
    }
#pragma unroll
    for (int k = 0; k < 8; ++k) {
        acc[k] += __shfl_xor(acc[k], 8);
        acc[k] += __shfl_xor(acc[k], 16);
        acc[k] += __shfl_xor(acc[k], 32);
    }
    if (slot == 0) {
        float di = dinv[node];
        float sc = di * di;
        uint4 hv = h4[(size_t)node * 8 + q];
        float4 o0, o1;
        o0.x = acc[0] + bf_lo(hv.x) * sc; o0.y = acc[1] + bf_hi(hv.x) * sc;
        o0.z = acc[2] + bf_lo(hv.y) * sc; o0.w = acc[3] + bf_hi(hv.y) * sc;
        o1.x = acc[4] + bf_lo(hv.z) * sc; o1.y = acc[5] + bf_hi(hv.z) * sc;
        o1.z = acc[6] + bf_lo(hv.w) * sc; o1.w = acc[7] + bf_hi(hv.w) * sc;
        ((float4*)out)[(size_t)node * 16 + q * 2] = o0;
        ((float4*)out)[(size_t)node * 16 + q * 2 + 1] = o1;
    }
}

// CSR aggregate, 32-wide bf16 rows (64 B), final layer. Wave per node:
// 16 slots x 4 lanes. Fuses self-loop, +b3, d_out write, spread mean buckets.
__global__ __launch_bounds__(256) void agg32_final_kernel(
    const ushort* __restrict__ h, const int2* __restrict__ edges,
    const int* __restrict__ offs, const float* __restrict__ dinv,
    const float* __restrict__ b3, float* __restrict__ out,
    float* __restrict__ mean_acc, int N) {
    __shared__ float ssum[32];
    if (threadIdx.x < 32) ssum[threadIdx.x] = 0.0f;
    __syncthreads();
    const int wave = threadIdx.x >> 6, lane = threadIdx.x & 63;
    const int node = blockIdx.x * 4 + wave;
    const int slot = lane >> 2;  // 0..15
    const int q = lane & 3;      // uint4 index within the 64 B row
    const uint4* __restrict__ h4 = (const uint4*)h;
    float acc[8] = {};
    if (node < N) {
        const int start = offs[node], end = offs[node + 1];
        for (int j = start + slot; j < end; j += 16) {
            int2 e0 = edges[j];
            uint4 u0 = h4[(size_t)e0.x * 4 + q];
            float n0 = __int_as_float(e0.y);
            acc[0] += bf_lo(u0.x) * n0; acc[1] += bf_hi(u0.x) * n0;
            acc[2] += bf_lo(u0.y) * n0; acc[3] += bf_hi(u0.y) * n0;
            acc[4] += bf_lo(u0.z) * n0; acc[5] += bf_hi(u0.z) * n0;
            acc[6] += bf_lo(u0.w) * n0; acc[7] += bf_hi(u0.w) * n0;
        }
    }
#pragma unroll
    for (int k = 0; k < 8; ++k) {
        acc[k] += __shfl_xor(acc[k], 4);
        acc[k] += __shfl_xor(acc[k], 8);
        acc[k] += __shfl_xor(acc[k], 16);
        acc[k] += __shfl_xor(acc[k], 32);
    }
    if (node < N && slot == 0) {
        float di = dinv[node];
        float sc = di * di;
        uint4 hv = h4[(size_t)node * 4 + q];
        const float4* b34 = (const float4*)b3;
        float4 bA = b34[q * 2], bB = b34[q * 2 + 1];
        float4 o0, o1;
        o0.x = acc[0] + bf_lo(hv.x) * sc + bA.x;
        o0.y = acc[1] + bf_hi(hv.x) * sc + bA.y;
        o0.z = acc[2] + bf_lo(hv.y) * sc + bA.z;
        o0.w = acc[3] + bf_hi(hv.y) * sc + bA.w;
        o1.x = acc[4] + bf_lo(hv.z) * sc + bB.x;
        o1.y = acc[5] + bf_hi(hv.z) * sc + bB.y;
        o1.z = acc[6] + bf_lo(hv.w) * sc + bB.z;
        o1.w = acc[7] + bf_hi(hv.w) * sc + bB.w;
        ((float4*)out)[(size_t)node * 8 + q * 2] = o0;
        ((float4*)out)[(size_t)node * 8 + q * 2 + 1] = o1;
        int fb = q * 8;
        atomicAdd(&ssum[fb + 0], o0.x); atomicAdd(&ssum[fb + 1], o0.y);
        atomicAdd(&ssum[fb + 2], o0.z); atomicAdd(&ssum[fb + 3], o0.w);
        atomicAdd(&ssum[fb + 4], o1.x); atomicAdd(&ssum[fb + 5], o1.y);
        atomicAdd(&ssum[fb + 6], o1.z); atomicAdd(&ssum[fb + 7], o1.w);
    }
    __syncthreads();
    if (threadIdx.x < 32) {
        // 128 spread buckets: contention 25000 blocks -> ~195 per address
        int bucket = blockIdx.x & 127;
        atomicAdd(&mean_acc[bucket * 32 + threadIdx.x], ssum[threadIdx.x]);
    }
}

__global__ void write_mean_kernel(const float* __restrict__ mean_acc,
                                  float* __restrict__ out_tail, float invN) {
    int f = threadIdx.x;
    if (f < 32) {
        float s = 0.0f;
        for (int b = 0; b < 128; ++b) s += mean_acc[b * 32 + f];
        out_tail[f] = s * invN;
    }
}

extern "C" void kernel_launch(void* const* d_in, const int* in_sizes, int n_in,
                              void* d_out, int out_size, void* d_ws,
                              size_t ws_size, hipStream_t stream) {
    const float* x  = (const float*)d_in[0];
    const int*   ei = (const int*)d_in[1];
    const float* ew = (const float*)d_in[2];
    const float* W1 = (const float*)d_in[3];
    const float* b1 = (const float*)d_in[4];
    const float* W2 = (const float*)d_in[5];
    const float* b2 = (const float*)d_in[6];
    const float* W3 = (const float*)d_in[7];
    const float* b3 = (const float*)d_in[8];

    const int N = in_sizes[0] / 128;
    const int E = in_sizes[1] / 2;
    const int* src = ei;
    const int* dst = ei + E;

    float* out = (float*)d_out;
    char* wsp = (char*)d_ws;
    auto carve = [&](size_t bytes) {
        char* p = wsp;
        wsp += (bytes + 255) & ~(size_t)255;
        return p;
    };
    float* deg      = (float*)carve((size_t)N * 4);
    int*   cnt      = (int*)carve((size_t)N * 4);
    int*   offs     = (int*)carve((size_t)(N + 1) * 4);
    int*   partials = (int*)carve(512 * 4);
    int*   cursor   = (int*)carve((size_t)N * 4);
    int2*  edges    = (int2*)carve((size_t)E * 8);
    ushort* hbuf    = (ushort*)carve((size_t)N * 64 * 2);  // bf16 activations
    float* aggbuf   = (float*)carve((size_t)N * 64 * 4);   // fp32 agg output
    float* mean     = (float*)carve(128 * 32 * 4);

    const int nb_n = (N + 255) / 256;
    const int nb_e = (E + 255) / 256;
    const int nb_a = (N + 3) / 4;  // aggregation: 4 nodes (waves) per block

    hipMemsetAsync(mean, 0, 128 * 32 * sizeof(float), stream);

    // ---- preprocessing: deg/dinv + CSR build (norm fused into scatter) ----
    init_kernel<<<nb_n, 256, 0, stream>>>(deg, cnt, N);
    deg_hist_kernel<<<nb_e, 256, 0, stream>>>(dst, ew, deg, cnt, E);
    dinv_kernel<<<nb_n, 256, 0, stream>>>(deg, N);
    scan_block_kernel<<<nb_n, 256, 0, stream>>>(cnt, offs, partials, N);
    scan_partials_kernel<<<1, 512, 0, stream>>>(partials, nb_n);
    add_offsets_kernel<<<nb_n, 256, 0, stream>>>(offs, partials, cursor, N, E);
    scatter_edges_kernel<<<nb_e, 256, 0, stream>>>(src, dst, ew, deg, cursor,
                                                   edges, E);

    // ---- layer 1: h1=bf16(x@W1); agg1=A h1 (fp32) ----
    gemm_kernel<128, 64, false, false>
        <<<(N + 15) / 16, 256, 0, stream>>>(x, W1, nullptr, hbuf, N);
    agg64_kernel<<<nb_a, 256, 0, stream>>>(hbuf, edges, offs, deg, aggbuf, N);

    // ---- layer 2: h2=bf16(relu(agg1+b1)@W2); agg2=A h2 ----
    gemm_kernel<64, 64, true, true>
        <<<(N + 15) / 16, 256, 0, stream>>>(aggbuf, W2, b1, hbuf, N);
    agg64_kernel<<<nb_a, 256, 0, stream>>>(hbuf, edges, offs, deg, aggbuf, N);

    // ---- layer 3: h3=bf16(relu(agg2+b2)@W3); out=A h3 + b3; mean pool ----
    gemm_kernel<64, 32, true, true>
        <<<(N + 15) / 16, 256, 0, stream>>>(aggbuf, W3, b2, hbuf, N);
    agg32_final_kernel<<<nb_a, 256, 0, stream>>>(hbuf, edges, offs, deg, b3,
                                                 out, mean, N);

    // ---- epilogue: fold mean buckets ----
    write_mean_kernel<<<1, 32, 0, stream>>>(mean, out + (size_t)N * 32,
                                            1.0f / (float)N);
}

// Round 5
// 480.581 us; speedup vs baseline: 2.8736x; 1.1751x over previous
//
#include <hip/hip_runtime.h>

// ---------------------------------------------------------------------------
// GCN 3-layer forward on MI355X — rank-based CSR build (1 atomic pass),
// bf16-staged activations end-to-end.
// Lesson R4: device atomics write through L2 at 32 B/op (deg_hist WRITE_SIZE
// = 2*E*32B exactly) => minimize atomic ops, derive deg/norm from CSR
// segments atomic-free.
// ---------------------------------------------------------------------------

typedef unsigned int uint32;

__device__ __forceinline__ ushort f2bf(float v) {
    uint32 u = __float_as_uint(v);
    u += 0x7fff + ((u >> 16) & 1);  // round to nearest even
    return (ushort)(u >> 16);
}
__device__ __forceinline__ uint32 pack2bf(float a, float b) {
    return (uint32)f2bf(a) | ((uint32)f2bf(b) << 16);
}
__device__ __forceinline__ float bf_lo(uint32 u) {
    return __uint_as_float(u << 16);
}
__device__ __forceinline__ float bf_hi(uint32 u) {
    return __uint_as_float(u & 0xffff0000u);
}

// ---- pass 1: rank[e] = arrival index of edge e within its dst bucket ----
__global__ void rank_kernel(const int* __restrict__ dst,
                            int* __restrict__ cnt, int* __restrict__ rank,
                            int E) {
    int e = blockIdx.x * blockDim.x + threadIdx.x;
    if (e < E) rank[e] = atomicAdd(&cnt[dst[e]], 1);
}

// ---- 2-level exclusive scan over cnt[N] -> offs[N+1] ----
__global__ void scan_block_kernel(const int* __restrict__ cnt,
                                  int* __restrict__ offs,
                                  int* __restrict__ partials, int N) {
    __shared__ int s[256];
    int i = blockIdx.x * 256 + threadIdx.x;
    int v = (i < N) ? cnt[i] : 0;
    s[threadIdx.x] = v;
    __syncthreads();
    for (int off = 1; off < 256; off <<= 1) {
        int t = (threadIdx.x >= off) ? s[threadIdx.x - off] : 0;
        __syncthreads();
        s[threadIdx.x] += t;
        __syncthreads();
    }
    if (i < N) offs[i] = s[threadIdx.x] - v;  // exclusive
    if (threadIdx.x == 255) partials[blockIdx.x] = s[255];
}

__global__ void scan_partials_kernel(int* __restrict__ partials, int P) {
    __shared__ int s[512];
    int v = (threadIdx.x < P) ? partials[threadIdx.x] : 0;
    s[threadIdx.x] = v;
    __syncthreads();
    for (int off = 1; off < 512; off <<= 1) {
        int t = (threadIdx.x >= off) ? s[threadIdx.x - off] : 0;
        __syncthreads();
        s[threadIdx.x] += t;
        __syncthreads();
    }
    if (threadIdx.x < P) partials[threadIdx.x] = s[threadIdx.x] - v;  // excl
}

__global__ void add_offsets_kernel(int* __restrict__ offs,
                                   const int* __restrict__ partials, int N,
                                   int E) {
    int i = blockIdx.x * 256 + threadIdx.x;
    if (i < N) offs[i] += partials[blockIdx.x];
    if (i == N - 1) offs[N] = E;
}

// ---- pass 2: atomic-free scatter into CSR slots; carries (src, ew) ----
__global__ void scatter_edges_kernel(const int* __restrict__ src,
                                     const int* __restrict__ dst,
                                     const float* __restrict__ ew,
                                     const int* __restrict__ offs,
                                     const int* __restrict__ rank,
                                     int2* __restrict__ edges, int E) {
    int e = blockIdx.x * blockDim.x + threadIdx.x;
    if (e < E) {
        int pos = offs[dst[e]] + rank[e];
        edges[pos] = make_int2(src[e], __float_as_int(ew[e]));
    }
}

// ---- deg via CSR segment sum (atomic-free): dinv[d] = rsqrt(1 + sum(ew)) ----
__global__ __launch_bounds__(256) void deg_kernel(
    const int2* __restrict__ edges, const int* __restrict__ offs,
    float* __restrict__ dinv, int N) {
    const int wave = threadIdx.x >> 6, lane = threadIdx.x & 63;
    const int node = blockIdx.x * 4 + wave;
    if (node >= N) return;
    const int start = offs[node], end = offs[node + 1];
    float s = 0.0f;
    for (int j = start + lane; j < end; j += 64)
        s += __int_as_float(edges[j].y);
    s += __shfl_xor(s, 1);  s += __shfl_xor(s, 2);
    s += __shfl_xor(s, 4);  s += __shfl_xor(s, 8);
    s += __shfl_xor(s, 16); s += __shfl_xor(s, 32);
    if (lane == 0) dinv[node] = rsqrtf(1.0f + s);  // self-loop weight 1
}

// ---- in-place ew -> norm: edges[j].y = dinv[src]*ew*dinv[dst] ----
__global__ __launch_bounds__(256) void norm_kernel(
    int2* __restrict__ edges, const int* __restrict__ offs,
    const float* __restrict__ dinv, int N) {
    const int wave = threadIdx.x >> 6, lane = threadIdx.x & 63;
    const int node = blockIdx.x * 4 + wave;
    if (node >= N) return;
    const float dd = dinv[node];
    const int start = offs[node], end = offs[node + 1];
    for (int j = start + lane; j < end; j += 64) {
        int2 e = edges[j];
        float nr = dinv[e.x] * __int_as_float(e.y) * dd;
        edges[j] = make_int2(e.x, __float_as_int(nr));
    }
}

// out_bf16[n][o] = f(in[n]) @ W; f = optional (+bias_in, relu). fp32 math.
template <int K, int M, bool RELU, bool BIAS, bool INBF16>
__global__ __launch_bounds__(256) void gemm_kernel(
    const void* __restrict__ in_, const float* __restrict__ W,
    const float* __restrict__ bias_in, ushort* __restrict__ out, int N) {
    constexpr int NPB = 16;  // nodes per block
    __shared__ __align__(16) float Wl[K * M];
    __shared__ __align__(16) float xl[NPB * K];
    const int tid = threadIdx.x;
    const int node0 = blockIdx.x * NPB;

    for (int i = tid; i < K * M / 4; i += 256)
        ((float4*)Wl)[i] = ((const float4*)W)[i];

    if (INBF16) {
        const uint4* in4 = (const uint4*)in_;  // 8 bf16 per uint4
        for (int i = tid; i < NPB * K / 8; i += 256) {
            int ln = i / (K / 8), kq = i % (K / 8);
            int node = node0 + ln;
            float v[8] = {0.f, 0.f, 0.f, 0.f, 0.f, 0.f, 0.f, 0.f};
            if (node < N) {
                uint4 u = in4[(size_t)node * (K / 8) + kq];
                v[0] = bf_lo(u.x); v[1] = bf_hi(u.x);
                v[2] = bf_lo(u.y); v[3] = bf_hi(u.y);
                v[4] = bf_lo(u.z); v[5] = bf_hi(u.z);
                v[6] = bf_lo(u.w); v[7] = bf_hi(u.w);
#pragma unroll
                for (int j = 0; j < 8; ++j) {
                    if (BIAS) v[j] += bias_in[kq * 8 + j];
                    if (RELU) v[j] = fmaxf(v[j], 0.f);
                }
            }
#pragma unroll
            for (int j = 0; j < 8; ++j) xl[ln * K + kq * 8 + j] = v[j];
        }
    } else {
        const float4* in4 = (const float4*)in_;
        for (int i = tid; i < NPB * K / 4; i += 256) {
            int ln = i / (K / 4), kq = i % (K / 4);
            int node = node0 + ln;
            float4 v = make_float4(0.f, 0.f, 0.f, 0.f);
            if (node < N) {
                v = in4[(size_t)node * (K / 4) + kq];
                if (BIAS) {
                    float4 b = ((const float4*)bias_in)[kq];
                    v.x += b.x; v.y += b.y; v.z += b.z; v.w += b.w;
                }
                if (RELU) {
                    v.x = fmaxf(v.x, 0.f); v.y = fmaxf(v.y, 0.f);
                    v.z = fmaxf(v.z, 0.f); v.w = fmaxf(v.w, 0.f);
                }
            }
            ((float4*)xl)[i] = v;
        }
    }
    __syncthreads();

    constexpr int GROUPS = 256 / M;
    constexpr int NPG = NPB / GROUPS;
    const int o = tid % M;
    const int g = tid / M;
    const float4* xl4 = (const float4*)xl;
    float acc[NPG] = {};
#pragma unroll 4
    for (int k = 0; k < K; k += 4) {
        float w0 = Wl[k * M + o];
        float w1 = Wl[(k + 1) * M + o];
        float w2 = Wl[(k + 2) * M + o];
        float w3 = Wl[(k + 3) * M + o];
#pragma unroll
        for (int jj = 0; jj < NPG; ++jj) {
            float4 xv = xl4[(g * NPG + jj) * (K / 4) + (k >> 2)];
            acc[jj] += xv.x * w0 + xv.y * w1 + xv.z * w2 + xv.w * w3;
        }
    }
#pragma unroll
    for (int jj = 0; jj < NPG; ++jj) {
        int node = node0 + g * NPG + jj;
        if (node < N) out[(size_t)node * M + o] = f2bf(acc[jj]);
    }
}

// CSR aggregate, 64-wide bf16 rows (128 B). Wave per node: 8 slots x 8
// uint4-lanes, unroll x2 => 16 rows in flight. fp32 accumulate, bf16 out.
__global__ __launch_bounds__(256) void agg64_kernel(
    const ushort* __restrict__ h, const int2* __restrict__ edges,
    const int* __restrict__ offs, const float* __restrict__ dinv,
    ushort* __restrict__ out, int N) {
    const int wave = threadIdx.x >> 6, lane = threadIdx.x & 63;
    const int node = blockIdx.x * 4 + wave;
    if (node >= N) return;
    const int slot = lane >> 3;  // 0..7
    const int q = lane & 7;      // uint4 index within the 128 B row
    const uint4* __restrict__ h4 = (const uint4*)h;
    const int start = offs[node], end = offs[node + 1];
    float acc[8] = {};
    int j = start + slot;
    for (; j + 8 < end; j += 16) {
        int2 e0 = edges[j];
        int2 e1 = edges[j + 8];
        uint4 u0 = h4[(size_t)e0.x * 8 + q];
        uint4 u1 = h4[(size_t)e1.x * 8 + q];
        float n0 = __int_as_float(e0.y), n1 = __int_as_float(e1.y);
        acc[0] += bf_lo(u0.x) * n0 + bf_lo(u1.x) * n1;
        acc[1] += bf_hi(u0.x) * n0 + bf_hi(u1.x) * n1;
        acc[2] += bf_lo(u0.y) * n0 + bf_lo(u1.y) * n1;
        acc[3] += bf_hi(u0.y) * n0 + bf_hi(u1.y) * n1;
        acc[4] += bf_lo(u0.z) * n0 + bf_lo(u1.z) * n1;
        acc[5] += bf_hi(u0.z) * n0 + bf_hi(u1.z) * n1;
        acc[6] += bf_lo(u0.w) * n0 + bf_lo(u1.w) * n1;
        acc[7] += bf_hi(u0.w) * n0 + bf_hi(u1.w) * n1;
    }
    if (j < end) {
        int2 e0 = edges[j];
        uint4 u0 = h4[(size_t)e0.x * 8 + q];
        float n0 = __int_as_float(e0.y);
        acc[0] += bf_lo(u0.x) * n0; acc[1] += bf_hi(u0.x) * n0;
        acc[2] += bf_lo(u0.y) * n0; acc[3] += bf_hi(u0.y) * n0;
        acc[4] += bf_lo(u0.z) * n0; acc[5] += bf_hi(u0.z) * n0;
        acc[6] += bf_lo(u0.w) * n0; acc[7] += bf_hi(u0.w) * n0;
    }
#pragma unroll
    for (int k = 0; k < 8; ++k) {
        acc[k] += __shfl_xor(acc[k], 8);
        acc[k] += __shfl_xor(acc[k], 16);
        acc[k] += __shfl_xor(acc[k], 32);
    }
    if (slot == 0) {
        float di = dinv[node];
        float sc = di * di;
        uint4 hv = h4[(size_t)node * 8 + q];
        uint4 o;
        o.x = pack2bf(acc[0] + bf_lo(hv.x) * sc, acc[1] + bf_hi(hv.x) * sc);
        o.y = pack2bf(acc[2] + bf_lo(hv.y) * sc, acc[3] + bf_hi(hv.y) * sc);
        o.z = pack2bf(acc[4] + bf_lo(hv.z) * sc, acc[5] + bf_hi(hv.z) * sc);
        o.w = pack2bf(acc[6] + bf_lo(hv.w) * sc, acc[7] + bf_hi(hv.w) * sc);
        ((uint4*)out)[(size_t)node * 8 + q] = o;
    }
}

// CSR aggregate, 32-wide bf16 rows (64 B), final layer. Wave per node:
// 16 slots x 4 lanes. Fuses self-loop, +b3, fp32 d_out, spread mean buckets.
__global__ __launch_bounds__(256) void agg32_final_kernel(
    const ushort* __restrict__ h, const int2* __restrict__ edges,
    const int* __restrict__ offs, const float* __restrict__ dinv,
    const float* __restrict__ b3, float* __restrict__ out,
    float* __restrict__ mean_acc, int N) {
    __shared__ float ssum[32];
    if (threadIdx.x < 32) ssum[threadIdx.x] = 0.0f;
    __syncthreads();
    const int wave = threadIdx.x >> 6, lane = threadIdx.x & 63;
    const int node = blockIdx.x * 4 + wave;
    const int slot = lane >> 2;  // 0..15
    const int q = lane & 3;      // uint4 index within the 64 B row
    const uint4* __restrict__ h4 = (const uint4*)h;
    float acc[8] = {};
    if (node < N) {
        const int start = offs[node], end = offs[node + 1];
        for (int j = start + slot; j < end; j += 16) {
            int2 e0 = edges[j];
            uint4 u0 = h4[(size_t)e0.x * 4 + q];
            float n0 = __int_as_float(e0.y);
            acc[0] += bf_lo(u0.x) * n0; acc[1] += bf_hi(u0.x) * n0;
            acc[2] += bf_lo(u0.y) * n0; acc[3] += bf_hi(u0.y) * n0;
            acc[4] += bf_lo(u0.z) * n0; acc[5] += bf_hi(u0.z) * n0;
            acc[6] += bf_lo(u0.w) * n0; acc[7] += bf_hi(u0.w) * n0;
        }
    }
#pragma unroll
    for (int k = 0; k < 8; ++k) {
        acc[k] += __shfl_xor(acc[k], 4);
        acc[k] += __shfl_xor(acc[k], 8);
        acc[k] += __shfl_xor(acc[k], 16);
        acc[k] += __shfl_xor(acc[k], 32);
    }
    if (node < N && slot == 0) {
        float di = dinv[node];
        float sc = di * di;
        uint4 hv = h4[(size_t)node * 4 + q];
        const float4* b34 = (const float4*)b3;
        float4 bA = b34[q * 2], bB = b34[q * 2 + 1];
        float4 o0, o1;
        o0.x = acc[0] + bf_lo(hv.x) * sc + bA.x;
        o0.y = acc[1] + bf_hi(hv.x) * sc + bA.y;
        o0.z = acc[2] + bf_lo(hv.y) * sc + bA.z;
        o0.w = acc[3] + bf_hi(hv.y) * sc + bA.w;
        o1.x = acc[4] + bf_lo(hv.z) * sc + bB.x;
        o1.y = acc[5] + bf_hi(hv.z) * sc + bB.y;
        o1.z = acc[6] + bf_lo(hv.w) * sc + bB.z;
        o1.w = acc[7] + bf_hi(hv.w) * sc + bB.w;
        ((float4*)out)[(size_t)node * 8 + q * 2] = o0;
        ((float4*)out)[(size_t)node * 8 + q * 2 + 1] = o1;
        int fb = q * 8;
        atomicAdd(&ssum[fb + 0], o0.x); atomicAdd(&ssum[fb + 1], o0.y);
        atomicAdd(&ssum[fb + 2], o0.z); atomicAdd(&ssum[fb + 3], o0.w);
        atomicAdd(&ssum[fb + 4], o1.x); atomicAdd(&ssum[fb + 5], o1.y);
        atomicAdd(&ssum[fb + 6], o1.z); atomicAdd(&ssum[fb + 7], o1.w);
    }
    __syncthreads();
    if (threadIdx.x < 32) {
        // 128 spread buckets: same-address contention 25000 -> ~195
        int bucket = blockIdx.x & 127;
        atomicAdd(&mean_acc[bucket * 32 + threadIdx.x], ssum[threadIdx.x]);
    }
}

__global__ void write_mean_kernel(const float* __restrict__ mean_acc,
                                  float* __restrict__ out_tail, float invN) {
    int f = threadIdx.x;
    if (f < 32) {
        float s = 0.0f;
        for (int b = 0; b < 128; ++b) s += mean_acc[b * 32 + f];
        out_tail[f] = s * invN;
    }
}

extern "C" void kernel_launch(void* const* d_in, const int* in_sizes, int n_in,
                              void* d_out, int out_size, void* d_ws,
                              size_t ws_size, hipStream_t stream) {
    const float* x  = (const float*)d_in[0];
    const int*   ei = (const int*)d_in[1];
    const float* ew = (const float*)d_in[2];
    const float* W1 = (const float*)d_in[3];
    const float* b1 = (const float*)d_in[4];
    const float* W2 = (const float*)d_in[5];
    const float* b2 = (const float*)d_in[6];
    const float* W3 = (const float*)d_in[7];
    const float* b3 = (const float*)d_in[8];

    const int N = in_sizes[0] / 128;
    const int E = in_sizes[1] / 2;
    const int* src = ei;
    const int* dst = ei + E;

    float* out = (float*)d_out;
    char* wsp = (char*)d_ws;
    auto carve = [&](size_t bytes) {
        char* p = wsp;
        wsp += (bytes + 255) & ~(size_t)255;
        return p;
    };
    float*  dinv     = (float*)carve((size_t)N * 4);
    int*    cnt      = (int*)carve((size_t)N * 4);
    int*    offs     = (int*)carve((size_t)(N + 1) * 4);
    int*    partials = (int*)carve(512 * 4);
    int*    rank     = (int*)carve((size_t)E * 4);
    int2*   edges    = (int2*)carve((size_t)E * 8);
    ushort* hA       = (ushort*)carve((size_t)N * 64 * 2);
    ushort* hB       = (ushort*)carve((size_t)N * 64 * 2);
    float*  mean     = (float*)carve(128 * 32 * 4);

    const int nb_n = (N + 255) / 256;
    const int nb_e = (E + 255) / 256;
    const int nb_a = (N + 3) / 4;  // wave-per-node kernels: 4 nodes/block

    hipMemsetAsync(cnt, 0, (size_t)N * sizeof(int), stream);
    hipMemsetAsync(mean, 0, 128 * 32 * sizeof(float), stream);

    // ---- CSR build: 1 atomic pass (rank), scan, atomic-free scatter ----
    rank_kernel<<<nb_e, 256, 0, stream>>>(dst, cnt, rank, E);
    scan_block_kernel<<<nb_n, 256, 0, stream>>>(cnt, offs, partials, N);
    scan_partials_kernel<<<1, 512, 0, stream>>>(partials, nb_n);
    add_offsets_kernel<<<nb_n, 256, 0, stream>>>(offs, partials, N, E);
    scatter_edges_kernel<<<nb_e, 256, 0, stream>>>(src, dst, ew, offs, rank,
                                                   edges, E);
    // ---- deg + norm from CSR segments (atomic-free) ----
    deg_kernel<<<nb_a, 256, 0, stream>>>(edges, offs, dinv, N);
    norm_kernel<<<nb_a, 256, 0, stream>>>(edges, offs, dinv, N);

    // ---- layer 1: hA = bf16(x @ W1); hB = A hA ----
    gemm_kernel<128, 64, false, false, false>
        <<<(N + 15) / 16, 256, 0, stream>>>(x, W1, nullptr, hA, N);
    agg64_kernel<<<nb_a, 256, 0, stream>>>(hA, edges, offs, dinv, hB, N);

    // ---- layer 2: hA = bf16(relu(hB + b1) @ W2); hB = A hA ----
    gemm_kernel<64, 64, true, true, true>
        <<<(N + 15) / 16, 256, 0, stream>>>(hB, W2, b1, hA, N);
    agg64_kernel<<<nb_a, 256, 0, stream>>>(hA, edges, offs, dinv, hB, N);

    // ---- layer 3: hA = bf16(relu(hB + b2) @ W3); out = A hA + b3; mean ----
    gemm_kernel<64, 32, true, true, true>
        <<<(N + 15) / 16, 256, 0, stream>>>(hB, W3, b2, hA, N);
    agg32_final_kernel<<<nb_a, 256, 0, stream>>>(hA, edges, offs, dinv, b3,
                                                 out, mean, N);

    // ---- epilogue: fold mean buckets ----
    write_mean_kernel<<<1, 32, 0, stream>>>(mean, out + (size_t)N * 32,
                                            1.0f / (float)N);
}

// Round 6
// 409.587 us; speedup vs baseline: 3.3717x; 1.1733x over previous
//
#include <hip/hip_runtime.h>

// ---------------------------------------------------------------------------
// GCN 3-layer forward on MI355X — atomic-free radix CSR build + bf16 staging.
// Lesson R5: random global atomics write through one 32B sector each
// (rank_kernel WRITE_SIZE == E*32B exactly) at ~765 GB/s => replace the
// atomic histogram with per-block LDS histograms over 196 coarse buckets
// (dst>>9), scans, bucket scatter, then per-bucket LDS counting sort that
// emits final CSR + offs and fuses deg->dinv (all of a node's in-edges live
// in its bucket). Zero global atomics in the whole build.
// ---------------------------------------------------------------------------

typedef unsigned int uint32;

#define G 256          // blocks in pass A / pass B
#define MAXB 256       // max coarse buckets (N <= 131072)

__device__ __forceinline__ ushort f2bf(float v) {
    uint32 u = __float_as_uint(v);
    u += 0x7fff + ((u >> 16) & 1);  // round to nearest even
    return (ushort)(u >> 16);
}
__device__ __forceinline__ uint32 pack2bf(float a, float b) {
    return (uint32)f2bf(a) | ((uint32)f2bf(b) << 16);
}
__device__ __forceinline__ float bf_lo(uint32 u) {
    return __uint_as_float(u << 16);
}
__device__ __forceinline__ float bf_hi(uint32 u) {
    return __uint_as_float(u & 0xffff0000u);
}

// ---- pass A: per-block LDS histogram over coarse buckets ----
__global__ __launch_bounds__(1024) void passA_hist_kernel(
    const int* __restrict__ dst, int* __restrict__ histG, int E, int EPB) {
    __shared__ int h[MAXB];
    const int tid = threadIdx.x, g = blockIdx.x;
    if (tid < MAXB) h[tid] = 0;
    __syncthreads();
    const int e0 = g * EPB, e1 = min(e0 + EPB, E);
    for (int e = e0 + tid; e < e1; e += 1024) atomicAdd(&h[dst[e] >> 9], 1);
    __syncthreads();
    if (tid < MAXB) histG[tid * G + g] = h[tid];  // layout [bucket][block]
}

// ---- bucket totals + exclusive scan -> bucketBase[NB+1] (1 block) ----
__global__ __launch_bounds__(256) void bucket_scan_kernel(
    const int* __restrict__ histG, int* __restrict__ bucketBase, int NB,
    int E) {
    __shared__ int s[256];
    const int t = threadIdx.x;
    int total = 0;
    if (t < NB)
        for (int g = 0; g < G; ++g) total += histG[t * G + g];
    s[t] = total;
    __syncthreads();
    for (int off = 1; off < 256; off <<= 1) {
        int v = (t >= off) ? s[t - off] : 0;
        __syncthreads();
        s[t] += v;
        __syncthreads();
    }
    if (t < NB) bucketBase[t] = s[t] - total;  // exclusive
    if (t == 0) bucketBase[NB] = E;
}

// ---- per-(bucket,block) write offsets: scan hist along blocks ----
__global__ __launch_bounds__(256) void block_offs_kernel(
    const int* __restrict__ histG, const int* __restrict__ bucketBase,
    int* __restrict__ blockOffs) {
    __shared__ int s[G];
    const int b = blockIdx.x, g = threadIdx.x;
    int v = histG[b * G + g];
    s[g] = v;
    __syncthreads();
    for (int off = 1; off < G; off <<= 1) {
        int u = (g >= off) ? s[g - off] : 0;
        __syncthreads();
        s[g] += u;
        __syncthreads();
    }
    blockOffs[b * G + g] = bucketBase[b] + s[g] - v;  // exclusive along g
}

// ---- pass B: scatter edges to their coarse-bucket segment (LDS cursors) ----
__global__ __launch_bounds__(1024) void passB_scatter_kernel(
    const int* __restrict__ src, const int* __restrict__ dst,
    const float* __restrict__ ew, const int* __restrict__ blockOffs,
    int2* __restrict__ tmp, int E, int EPB, int NB) {
    __shared__ int cur[MAXB];
    const int tid = threadIdx.x, g = blockIdx.x;
    if (tid < MAXB) cur[tid] = (tid < NB) ? blockOffs[tid * G + g] : 0;
    __syncthreads();
    const int e0 = g * EPB, e1 = min(e0 + EPB, E);
    for (int e = e0 + tid; e < e1; e += 1024) {
        int d = dst[e];
        int b = d >> 9;
        int pos = atomicAdd(&cur[b], 1);  // LDS atomic
        // pack: src (<2^17) | local-dst (9 bits) << 17 ; .y = ew bits
        tmp[pos] = make_int2(src[e] | ((d & 511) << 17),
                             __float_as_int(ew[e]));
    }
}

// ---- fine pass: per-bucket LDS counting sort -> final CSR + offs + dinv ----
__global__ __launch_bounds__(512) void fine_kernel(
    const int2* __restrict__ tmp, const int* __restrict__ bucketBase,
    int* __restrict__ offs, int2* __restrict__ edges,
    float* __restrict__ dinv, int N, int E, int NB) {
    __shared__ int cnt[512];
    __shared__ int excl[512];
    __shared__ float degf[512];
    const int t = threadIdx.x, b = blockIdx.x;
    const int base = bucketBase[b], endb = bucketBase[b + 1];
    cnt[t] = 0;
    degf[t] = 0.0f;
    __syncthreads();
    for (int j = base + t; j < endb; j += 512)
        atomicAdd(&cnt[(tmp[j].x >> 17) & 511], 1);
    __syncthreads();
    int v = cnt[t];
    excl[t] = v;
    __syncthreads();
    for (int off = 1; off < 512; off <<= 1) {  // Hillis-Steele inclusive
        int u = (t >= off) ? excl[t - off] : 0;
        __syncthreads();
        excl[t] += u;
        __syncthreads();
    }
    int myExcl = excl[t] - v;
    __syncthreads();
    excl[t] = myExcl;   // exclusive prefix
    cnt[t] = 0;         // reuse as scatter cursor
    __syncthreads();
    const int node0 = b << 9;
    const int node = node0 + t;
    if (node < N) offs[node] = base + myExcl;
    if (b == NB - 1 && t == 0) offs[N] = E;
    for (int j = base + t; j < endb; j += 512) {
        int2 ed = tmp[j];
        int ldst = (ed.x >> 17) & 511;
        int pos = base + excl[ldst] + atomicAdd(&cnt[ldst], 1);
        edges[pos] = make_int2(ed.x & 0x1FFFF, ed.y);
        atomicAdd(&degf[ldst], __int_as_float(ed.y));  // LDS float atomic
    }
    __syncthreads();
    if (node < N) dinv[node] = rsqrtf(1.0f + degf[t]);  // self-loop weight 1
}

// ---- in-place ew -> norm: edges[j].y = dinv[src]*ew*dinv[dst] ----
__global__ __launch_bounds__(256) void norm_kernel(
    int2* __restrict__ edges, const int* __restrict__ offs,
    const float* __restrict__ dinv, int N) {
    const int wave = threadIdx.x >> 6, lane = threadIdx.x & 63;
    const int node = blockIdx.x * 4 + wave;
    if (node >= N) return;
    const float dd = dinv[node];
    const int start = offs[node], end = offs[node + 1];
    for (int j = start + lane; j < end; j += 64) {
        int2 e = edges[j];
        float nr = dinv[e.x] * __int_as_float(e.y) * dd;
        edges[j] = make_int2(e.x, __float_as_int(nr));
    }
}

// out_bf16[n][o] = f(in[n]) @ W; f = optional (+bias_in, relu). fp32 math.
template <int K, int M, bool RELU, bool BIAS, bool INBF16>
__global__ __launch_bounds__(256) void gemm_kernel(
    const void* __restrict__ in_, const float* __restrict__ W,
    const float* __restrict__ bias_in, ushort* __restrict__ out, int N) {
    constexpr int NPB = 16;  // nodes per block
    __shared__ __align__(16) float Wl[K * M];
    __shared__ __align__(16) float xl[NPB * K];
    const int tid = threadIdx.x;
    const int node0 = blockIdx.x * NPB;

    for (int i = tid; i < K * M / 4; i += 256)
        ((float4*)Wl)[i] = ((const float4*)W)[i];

    if (INBF16) {
        const uint4* in4 = (const uint4*)in_;  // 8 bf16 per uint4
        for (int i = tid; i < NPB * K / 8; i += 256) {
            int ln = i / (K / 8), kq = i % (K / 8);
            int node = node0 + ln;
            float v[8] = {0.f, 0.f, 0.f, 0.f, 0.f, 0.f, 0.f, 0.f};
            if (node < N) {
                uint4 u = in4[(size_t)node * (K / 8) + kq];
                v[0] = bf_lo(u.x); v[1] = bf_hi(u.x);
                v[2] = bf_lo(u.y); v[3] = bf_hi(u.y);
                v[4] = bf_lo(u.z); v[5] = bf_hi(u.z);
                v[6] = bf_lo(u.w); v[7] = bf_hi(u.w);
#pragma unroll
                for (int j = 0; j < 8; ++j) {
                    if (BIAS) v[j] += bias_in[kq * 8 + j];
                    if (RELU) v[j] = fmaxf(v[j], 0.f);
                }
            }
#pragma unroll
            for (int j = 0; j < 8; ++j) xl[ln * K + kq * 8 + j] = v[j];
        }
    } else {
        const float4* in4 = (const float4*)in_;
        for (int i = tid; i < NPB * K / 4; i += 256) {
            int ln = i / (K / 4), kq = i % (K / 4);
            int node = node0 + ln;
            float4 v = make_float4(0.f, 0.f, 0.f, 0.f);
            if (node < N) {
                v = in4[(size_t)node * (K / 4) + kq];
                if (BIAS) {
                    float4 b = ((const float4*)bias_in)[kq];
                    v.x += b.x; v.y += b.y; v.z += b.z; v.w += b.w;
                }
                if (RELU) {
                    v.x = fmaxf(v.x, 0.f); v.y = fmaxf(v.y, 0.f);
                    v.z = fmaxf(v.z, 0.f); v.w = fmaxf(v.w, 0.f);
                }
            }
            ((float4*)xl)[i] = v;
        }
    }
    __syncthreads();

    constexpr int GROUPS = 256 / M;
    constexpr int NPG = NPB / GROUPS;
    const int o = tid % M;
    const int g = tid / M;
    const float4* xl4 = (const float4*)xl;
    float acc[NPG] = {};
#pragma unroll 4
    for (int k = 0; k < K; k += 4) {
        float w0 = Wl[k * M + o];
        float w1 = Wl[(k + 1) * M + o];
        float w2 = Wl[(k + 2) * M + o];
        float w3 = Wl[(k + 3) * M + o];
#pragma unroll
        for (int jj = 0; jj < NPG; ++jj) {
            float4 xv = xl4[(g * NPG + jj) * (K / 4) + (k >> 2)];
            acc[jj] += xv.x * w0 + xv.y * w1 + xv.z * w2 + xv.w * w3;
        }
    }
#pragma unroll
    for (int jj = 0; jj < NPG; ++jj) {
        int node = node0 + g * NPG + jj;
        if (node < N) out[(size_t)node * M + o] = f2bf(acc[jj]);
    }
}

// CSR aggregate, 64-wide bf16 rows (128 B). Wave per node: 8 slots x 8
// uint4-lanes, unroll x2 => 16 rows in flight. fp32 accumulate, bf16 out.
__global__ __launch_bounds__(256) void agg64_kernel(
    const ushort* __restrict__ h, const int2* __restrict__ edges,
    const int* __restrict__ offs, const float* __restrict__ dinv,
    ushort* __restrict__ out, int N) {
    const int wave = threadIdx.x >> 6, lane = threadIdx.x & 63;
    const int node = blockIdx.x * 4 + wave;
    if (node >= N) return;
    const int slot = lane >> 3;  // 0..7
    const int q = lane & 7;      // uint4 index within the 128 B row
    const uint4* __restrict__ h4 = (const uint4*)h;
    const int start = offs[node], end = offs[node + 1];
    float acc[8] = {};
    int j = start + slot;
    for (; j + 8 < end; j += 16) {
        int2 e0 = edges[j];
        int2 e1 = edges[j + 8];
        uint4 u0 = h4[(size_t)e0.x * 8 + q];
        uint4 u1 = h4[(size_t)e1.x * 8 + q];
        float n0 = __int_as_float(e0.y), n1 = __int_as_float(e1.y);
        acc[0] += bf_lo(u0.x) * n0 + bf_lo(u1.x) * n1;
        acc[1] += bf_hi(u0.x) * n0 + bf_hi(u1.x) * n1;
        acc[2] += bf_lo(u0.y) * n0 + bf_lo(u1.y) * n1;
        acc[3] += bf_hi(u0.y) * n0 + bf_hi(u1.y) * n1;
        acc[4] += bf_lo(u0.z) * n0 + bf_lo(u1.z) * n1;
        acc[5] += bf_hi(u0.z) * n0 + bf_hi(u1.z) * n1;
        acc[6] += bf_lo(u0.w) * n0 + bf_lo(u1.w) * n1;
        acc[7] += bf_hi(u0.w) * n0 + bf_hi(u1.w) * n1;
    }
    if (j < end) {
        int2 e0 = edges[j];
        uint4 u0 = h4[(size_t)e0.x * 8 + q];
        float n0 = __int_as_float(e0.y);
        acc[0] += bf_lo(u0.x) * n0; acc[1] += bf_hi(u0.x) * n0;
        acc[2] += bf_lo(u0.y) * n0; acc[3] += bf_hi(u0.y) * n0;
        acc[4] += bf_lo(u0.z) * n0; acc[5] += bf_hi(u0.z) * n0;
        acc[6] += bf_lo(u0.w) * n0; acc[7] += bf_hi(u0.w) * n0;
    }
#pragma unroll
    for (int k = 0; k < 8; ++k) {
        acc[k] += __shfl_xor(acc[k], 8);
        acc[k] += __shfl_xor(acc[k], 16);
        acc[k] += __shfl_xor(acc[k], 32);
    }
    if (slot == 0) {
        float di = dinv[node];
        float sc = di * di;
        uint4 hv = h4[(size_t)node * 8 + q];
        uint4 o;
        o.x = pack2bf(acc[0] + bf_lo(hv.x) * sc, acc[1] + bf_hi(hv.x) * sc);
        o.y = pack2bf(acc[2] + bf_lo(hv.y) * sc, acc[3] + bf_hi(hv.y) * sc);
        o.z = pack2bf(acc[4] + bf_lo(hv.z) * sc, acc[5] + bf_hi(hv.z) * sc);
        o.w = pack2bf(acc[6] + bf_lo(hv.w) * sc, acc[7] + bf_hi(hv.w) * sc);
        ((uint4*)out)[(size_t)node * 8 + q] = o;
    }
}

// CSR aggregate, 32-wide bf16 rows (64 B), final layer. Wave per node:
// 16 slots x 4 lanes. Fuses self-loop, +b3, fp32 d_out, spread mean buckets.
__global__ __launch_bounds__(256) void agg32_final_kernel(
    const ushort* __restrict__ h, const int2* __restrict__ edges,
    const int* __restrict__ offs, const float* __restrict__ dinv,
    const float* __restrict__ b3, float* __restrict__ out,
    float* __restrict__ mean_acc, int N) {
    __shared__ float ssum[32];
    if (threadIdx.x < 32) ssum[threadIdx.x] = 0.0f;
    __syncthreads();
    const int wave = threadIdx.x >> 6, lane = threadIdx.x & 63;
    const int node = blockIdx.x * 4 + wave;
    const int slot = lane >> 2;  // 0..15
    const int q = lane & 3;      // uint4 index within the 64 B row
    const uint4* __restrict__ h4 = (const uint4*)h;
    float acc[8] = {};
    if (node < N) {
        const int start = offs[node], end = offs[node + 1];
        for (int j = start + slot; j < end; j += 16) {
            int2 e0 = edges[j];
            uint4 u0 = h4[(size_t)e0.x * 4 + q];
            float n0 = __int_as_float(e0.y);
            acc[0] += bf_lo(u0.x) * n0; acc[1] += bf_hi(u0.x) * n0;
            acc[2] += bf_lo(u0.y) * n0; acc[3] += bf_hi(u0.y) * n0;
            acc[4] += bf_lo(u0.z) * n0; acc[5] += bf_hi(u0.z) * n0;
            acc[6] += bf_lo(u0.w) * n0; acc[7] += bf_hi(u0.w) * n0;
        }
    }
#pragma unroll
    for (int k = 0; k < 8; ++k) {
        acc[k] += __shfl_xor(acc[k], 4);
        acc[k] += __shfl_xor(acc[k], 8);
        acc[k] += __shfl_xor(acc[k], 16);
        acc[k] += __shfl_xor(acc[k], 32);
    }
    if (node < N && slot == 0) {
        float di = dinv[node];
        float sc = di * di;
        uint4 hv = h4[(size_t)node * 4 + q];
        const float4* b34 = (const float4*)b3;
        float4 bA = b34[q * 2], bB = b34[q * 2 + 1];
        float4 o0, o1;
        o0.x = acc[0] + bf_lo(hv.x) * sc + bA.x;
        o0.y = acc[1] + bf_hi(hv.x) * sc + bA.y;
        o0.z = acc[2] + bf_lo(hv.y) * sc + bA.z;
        o0.w = acc[3] + bf_hi(hv.y) * sc + bA.w;
        o1.x = acc[4] + bf_lo(hv.z) * sc + bB.x;
        o1.y = acc[5] + bf_hi(hv.z) * sc + bB.y;
        o1.z = acc[6] + bf_lo(hv.w) * sc + bB.z;
        o1.w = acc[7] + bf_hi(hv.w) * sc + bB.w;
        ((float4*)out)[(size_t)node * 8 + q * 2] = o0;
        ((float4*)out)[(size_t)node * 8 + q * 2 + 1] = o1;
        int fb = q * 8;
        atomicAdd(&ssum[fb + 0], o0.x); atomicAdd(&ssum[fb + 1], o0.y);
        atomicAdd(&ssum[fb + 2], o0.z); atomicAdd(&ssum[fb + 3], o0.w);
        atomicAdd(&ssum[fb + 4], o1.x); atomicAdd(&ssum[fb + 5], o1.y);
        atomicAdd(&ssum[fb + 6], o1.z); atomicAdd(&ssum[fb + 7], o1.w);
    }
    __syncthreads();
    if (threadIdx.x < 32) {
        // 128 spread buckets: same-address contention 25000 -> ~195
        int bucket = blockIdx.x & 127;
        atomicAdd(&mean_acc[bucket * 32 + threadIdx.x], ssum[threadIdx.x]);
    }
}

__global__ void write_mean_kernel(const float* __restrict__ mean_acc,
                                  float* __restrict__ out_tail, float invN) {
    int f = threadIdx.x;
    if (f < 32) {
        float s = 0.0f;
        for (int b = 0; b < 128; ++b) s += mean_acc[b * 32 + f];
        out_tail[f] = s * invN;
    }
}

extern "C" void kernel_launch(void* const* d_in, const int* in_sizes, int n_in,
                              void* d_out, int out_size, void* d_ws,
                              size_t ws_size, hipStream_t stream) {
    const float* x  = (const float*)d_in[0];
    const int*   ei = (const int*)d_in[1];
    const float* ew = (const float*)d_in[2];
    const float* W1 = (const float*)d_in[3];
    const float* b1 = (const float*)d_in[4];
    const float* W2 = (const float*)d_in[5];
    const float* b2 = (const float*)d_in[6];
    const float* W3 = (const float*)d_in[7];
    const float* b3 = (const float*)d_in[8];

    const int N = in_sizes[0] / 128;
    const int E = in_sizes[1] / 2;
    const int* src = ei;
    const int* dst = ei + E;

    const int NB = (N + 511) >> 9;          // coarse buckets (<= 256)
    const int EPB = (E + G - 1) / G;        // edges per pass-A/B block

    float* out = (float*)d_out;
    char* wsp = (char*)d_ws;
    auto carve = [&](size_t bytes) {
        char* p = wsp;
        wsp += (bytes + 255) & ~(size_t)255;
        return p;
    };
    float*  dinv       = (float*)carve((size_t)N * 4);
    int*    offs       = (int*)carve((size_t)(N + 1) * 4);
    int*    bucketBase = (int*)carve((MAXB + 1) * 4);
    int*    histG      = (int*)carve((size_t)MAXB * G * 4);
    int*    blockOffs  = (int*)carve((size_t)MAXB * G * 4);
    int2*   tmp        = (int2*)carve((size_t)E * 8);
    int2*   edges      = (int2*)carve((size_t)E * 8);
    ushort* hA         = (ushort*)carve((size_t)N * 64 * 2);
    ushort* hB         = (ushort*)carve((size_t)N * 64 * 2);
    float*  mean       = (float*)carve(128 * 32 * 4);

    const int nb_a = (N + 3) / 4;  // wave-per-node kernels: 4 nodes/block

    hipMemsetAsync(mean, 0, 128 * 32 * sizeof(float), stream);

    // ---- CSR build: LDS histograms -> scans -> bucket scatter -> fine sort
    //      (fine pass also emits offs and dinv). Zero global atomics. ----
    passA_hist_kernel<<<G, 1024, 0, stream>>>(dst, histG, E, EPB);
    bucket_scan_kernel<<<1, 256, 0, stream>>>(histG, bucketBase, NB, E);
    block_offs_kernel<<<NB, G, 0, stream>>>(histG, bucketBase, blockOffs);
    passB_scatter_kernel<<<G, 1024, 0, stream>>>(src, dst, ew, blockOffs, tmp,
                                                 E, EPB, NB);
    fine_kernel<<<NB, 512, 0, stream>>>(tmp, bucketBase, offs, edges, dinv, N,
                                        E, NB);
    norm_kernel<<<nb_a, 256, 0, stream>>>(edges, offs, dinv, N);

    // ---- layer 1: hA = bf16(x @ W1); hB = A hA ----
    gemm_kernel<128, 64, false, false, false>
        <<<(N + 15) / 16, 256, 0, stream>>>(x, W1, nullptr, hA, N);
    agg64_kernel<<<nb_a, 256, 0, stream>>>(hA, edges, offs, dinv, hB, N);

    // ---- layer 2: hA = bf16(relu(hB + b1) @ W2); hB = A hA ----
    gemm_kernel<64, 64, true, true, true>
        <<<(N + 15) / 16, 256, 0, stream>>>(hB, W2, b1, hA, N);
    agg64_kernel<<<nb_a, 256, 0, stream>>>(hA, edges, offs, dinv, hB, N);

    // ---- layer 3: hA = bf16(relu(hB + b2) @ W3); out = A hA + b3; mean ----
    gemm_kernel<64, 32, true, true, true>
        <<<(N + 15) / 16, 256, 0, stream>>>(hB, W3, b2, hA, N);
    agg32_final_kernel<<<nb_a, 256, 0, stream>>>(hA, edges, offs, dinv, b3,
                                                 out, mean, N);

    // ---- epilogue: fold mean buckets ----
    write_mean_kernel<<<1, 32, 0, stream>>>(mean, out + (size_t)N * 32,
                                            1.0f / (float)N);
}

// Round 7
// 361.220 us; speedup vs baseline: 3.8232x; 1.1339x over previous
//
#include <hip/hip_runtime.h>

// ---------------------------------------------------------------------------
// GCN 3-layer forward on MI355X — radix CSR build + bf16 MFMA GEMMs.
// Lesson R6: fp32 vector GEMM was LDS/VALU-bound (VALUBusy 63%, MfmaUtil 0,
// ~70 LDS-cyc per 16 FMA). All GEMMs now use v_mfma_f32_16x16x32_bf16 with
// bf16 LDS staging (padded +8 bf16/row to avoid bank aliasing), W
// pre-transposed to bf16 once per call. Layouts per verified m89 mapping.
// ---------------------------------------------------------------------------

typedef unsigned int uint32;
typedef __attribute__((ext_vector_type(8))) short bf16x8;
typedef __attribute__((ext_vector_type(4))) float f32x4;

#define G 256          // blocks in pass A / pass B
#define MAXB 256       // max coarse buckets (N <= 131072)

__device__ __forceinline__ ushort f2bf(float v) {
    uint32 u = __float_as_uint(v);
    u += 0x7fff + ((u >> 16) & 1);  // round to nearest even
    return (ushort)(u >> 16);
}
__device__ __forceinline__ uint32 pack2bf(float a, float b) {
    return (uint32)f2bf(a) | ((uint32)f2bf(b) << 16);
}
__device__ __forceinline__ float bf_lo(uint32 u) {
    return __uint_as_float(u << 16);
}
__device__ __forceinline__ float bf_hi(uint32 u) {
    return __uint_as_float(u & 0xffff0000u);
}

// ---- pass A: per-block LDS histogram over coarse buckets ----
__global__ __launch_bounds__(1024) void passA_hist_kernel(
    const int* __restrict__ dst, int* __restrict__ histG, int E, int EPB) {
    __shared__ int h[MAXB];
    const int tid = threadIdx.x, g = blockIdx.x;
    if (tid < MAXB) h[tid] = 0;
    __syncthreads();
    const int e0 = g * EPB, e1 = min(e0 + EPB, E);
    for (int e = e0 + tid; e < e1; e += 1024) atomicAdd(&h[dst[e] >> 9], 1);
    __syncthreads();
    if (tid < MAXB) histG[tid * G + g] = h[tid];  // layout [bucket][block]
}

// ---- bucket totals + exclusive scan -> bucketBase[NB+1] (1 block) ----
__global__ __launch_bounds__(256) void bucket_scan_kernel(
    const int* __restrict__ histG, int* __restrict__ bucketBase, int NB,
    int E) {
    __shared__ int s[256];
    const int t = threadIdx.x;
    int total = 0;
    if (t < NB)
        for (int g = 0; g < G; ++g) total += histG[t * G + g];
    s[t] = total;
    __syncthreads();
    for (int off = 1; off < 256; off <<= 1) {
        int v = (t >= off) ? s[t - off] : 0;
        __syncthreads();
        s[t] += v;
        __syncthreads();
    }
    if (t < NB) bucketBase[t] = s[t] - total;  // exclusive
    if (t == 0) bucketBase[NB] = E;
}

// ---- per-(bucket,block) write offsets: scan hist along blocks ----
__global__ __launch_bounds__(256) void block_offs_kernel(
    const int* __restrict__ histG, const int* __restrict__ bucketBase,
    int* __restrict__ blockOffs) {
    __shared__ int s[G];
    const int b = blockIdx.x, g = threadIdx.x;
    int v = histG[b * G + g];
    s[g] = v;
    __syncthreads();
    for (int off = 1; off < G; off <<= 1) {
        int u = (g >= off) ? s[g - off] : 0;
        __syncthreads();
        s[g] += u;
        __syncthreads();
    }
    blockOffs[b * G + g] = bucketBase[b] + s[g] - v;  // exclusive along g
}

// ---- pass B: scatter edges to their coarse-bucket segment (LDS cursors) ----
__global__ __launch_bounds__(1024) void passB_scatter_kernel(
    const int* __restrict__ src, const int* __restrict__ dst,
    const float* __restrict__ ew, const int* __restrict__ blockOffs,
    int2* __restrict__ tmp, int E, int EPB, int NB) {
    __shared__ int cur[MAXB];
    const int tid = threadIdx.x, g = blockIdx.x;
    if (tid < MAXB) cur[tid] = (tid < NB) ? blockOffs[tid * G + g] : 0;
    __syncthreads();
    const int e0 = g * EPB, e1 = min(e0 + EPB, E);
    for (int e = e0 + tid; e < e1; e += 1024) {
        int d = dst[e];
        int b = d >> 9;
        int pos = atomicAdd(&cur[b], 1);  // LDS atomic
        // pack: src (<2^17) | local-dst (9 bits) << 17 ; .y = ew bits
        tmp[pos] = make_int2(src[e] | ((d & 511) << 17),
                             __float_as_int(ew[e]));
    }
}

// ---- fine pass: per-bucket LDS counting sort -> final CSR + offs + dinv ----
__global__ __launch_bounds__(512) void fine_kernel(
    const int2* __restrict__ tmp, const int* __restrict__ bucketBase,
    int* __restrict__ offs, int2* __restrict__ edges,
    float* __restrict__ dinv, int N, int E, int NB) {
    __shared__ int cnt[512];
    __shared__ int excl[512];
    __shared__ float degf[512];
    const int t = threadIdx.x, b = blockIdx.x;
    const int base = bucketBase[b], endb = bucketBase[b + 1];
    cnt[t] = 0;
    degf[t] = 0.0f;
    __syncthreads();
    for (int j = base + t; j < endb; j += 512)
        atomicAdd(&cnt[(tmp[j].x >> 17) & 511], 1);
    __syncthreads();
    int v = cnt[t];
    excl[t] = v;
    __syncthreads();
    for (int off = 1; off < 512; off <<= 1) {  // Hillis-Steele inclusive
        int u = (t >= off) ? excl[t - off] : 0;
        __syncthreads();
        excl[t] += u;
        __syncthreads();
    }
    int myExcl = excl[t] - v;
    __syncthreads();
    excl[t] = myExcl;   // exclusive prefix
    cnt[t] = 0;         // reuse as scatter cursor
    __syncthreads();
    const int node0 = b << 9;
    const int node = node0 + t;
    if (node < N) offs[node] = base + myExcl;
    if (b == NB - 1 && t == 0) offs[N] = E;
    for (int j = base + t; j < endb; j += 512) {
        int2 ed = tmp[j];
        int ldst = (ed.x >> 17) & 511;
        int pos = base + excl[ldst] + atomicAdd(&cnt[ldst], 1);
        edges[pos] = make_int2(ed.x & 0x1FFFF, ed.y);
        atomicAdd(&degf[ldst], __int_as_float(ed.y));  // LDS float atomic
    }
    __syncthreads();
    if (node < N) dinv[node] = rsqrtf(1.0f + degf[t]);  // self-loop weight 1
}

// ---- in-place ew -> norm: edges[j].y = dinv[src]*ew*dinv[dst] ----
__global__ __launch_bounds__(256) void norm_kernel(
    int2* __restrict__ edges, const int* __restrict__ offs,
    const float* __restrict__ dinv, int N) {
    const int wave = threadIdx.x >> 6, lane = threadIdx.x & 63;
    const int node = blockIdx.x * 4 + wave;
    if (node >= N) return;
    const float dd = dinv[node];
    const int start = offs[node], end = offs[node + 1];
    for (int j = start + lane; j < end; j += 64) {
        int2 e = edges[j];
        float nr = dinv[e.x] * __int_as_float(e.y) * dd;
        edges[j] = make_int2(e.x, __float_as_int(nr));
    }
}

// ---- W [K][M] fp32 -> WT [M][K] bf16 (once per call, tiny) ----
__global__ void wt_kernel(const float* __restrict__ W,
                          ushort* __restrict__ WT, int K, int M) {
    int i = blockIdx.x * 256 + threadIdx.x;
    if (i < K * M) {
        int k = i / M, m = i % M;
        WT[m * K + k] = f2bf(W[i]);
    }
}

// ---- MFMA GEMM: out_bf16[N][M] = f(in[N][K]) @ W.  4 waves x 16-row tile,
// v_mfma_f32_16x16x32_bf16. A: X rows; B: WT rows (= W cols). LDS rows
// padded +8 bf16 (keeps 16B align, spreads banks: m*((K+8)/2)%32 = 4m). ----
template <int K, int M, bool RELU, bool BIAS, bool INBF16>
__global__ __launch_bounds__(256) void gemm_mfma_kernel(
    const void* __restrict__ in_, const ushort* __restrict__ WT,
    const float* __restrict__ bias_in, ushort* __restrict__ out, int N) {
    constexpr int KP = K + 8;    // padded LDS row stride (bf16 units)
    constexpr int CCH = M / 16;  // col chunks
    __shared__ __align__(16) ushort Xl[64 * KP];
    __shared__ __align__(16) ushort Wl[M * KP];
    const int tid = threadIdx.x;
    const int node0 = blockIdx.x * 64;

    // stage W^T (compact bf16 [M][K]) -> padded LDS
    for (int i = tid; i < M * (K / 8); i += 256) {
        int row = i / (K / 8), kc = i % (K / 8);
        uint4 u = ((const uint4*)WT)[i];
        *(uint4*)&Wl[row * KP + kc * 8] = u;
    }
    // stage X -> bf16 padded LDS (bias+relu fused for bf16 inputs)
    if (INBF16) {
        for (int i = tid; i < 64 * (K / 8); i += 256) {
            int row = i / (K / 8), kc = i % (K / 8);
            int node = node0 + row;
            uint4 u = make_uint4(0, 0, 0, 0);
            if (node < N) {
                u = ((const uint4*)in_)[(size_t)node * (K / 8) + kc];
                if (BIAS || RELU) {
                    float v[8];
                    v[0] = bf_lo(u.x); v[1] = bf_hi(u.x);
                    v[2] = bf_lo(u.y); v[3] = bf_hi(u.y);
                    v[4] = bf_lo(u.z); v[5] = bf_hi(u.z);
                    v[6] = bf_lo(u.w); v[7] = bf_hi(u.w);
#pragma unroll
                    for (int j = 0; j < 8; ++j) {
                        if (BIAS) v[j] += bias_in[kc * 8 + j];
                        if (RELU) v[j] = fmaxf(v[j], 0.f);
                    }
                    u.x = pack2bf(v[0], v[1]); u.y = pack2bf(v[2], v[3]);
                    u.z = pack2bf(v[4], v[5]); u.w = pack2bf(v[6], v[7]);
                }
            }
            *(uint4*)&Xl[row * KP + kc * 8] = u;
        }
    } else {
        for (int i = tid; i < 64 * (K / 4); i += 256) {
            int row = i / (K / 4), kc = i % (K / 4);
            int node = node0 + row;
            uint2 p = make_uint2(0, 0);
            if (node < N) {
                float4 v = ((const float4*)in_)[(size_t)node * (K / 4) + kc];
                p.x = pack2bf(v.x, v.y);
                p.y = pack2bf(v.z, v.w);
            }
            *(uint2*)&Xl[row * KP + kc * 4] = p;
        }
    }
    __syncthreads();

    const int wv = tid >> 6, lane = tid & 63;
    const int r16 = lane & 15, quad = lane >> 4;
    f32x4 acc[CCH];
#pragma unroll
    for (int c = 0; c < CCH; ++c) acc[c] = (f32x4){0.f, 0.f, 0.f, 0.f};
#pragma unroll
    for (int kq = 0; kq < K / 32; ++kq) {
        // A[m=lane&15][k=quad*8+j] (m89-verified layout)
        bf16x8 a = *(const bf16x8*)
            &Xl[(wv * 16 + r16) * KP + kq * 32 + quad * 8];
#pragma unroll
        for (int c = 0; c < CCH; ++c) {
            // B[k=quad*8+j][n=lane&15] == WT row (c*16+n)
            bf16x8 b = *(const bf16x8*)
                &Wl[(c * 16 + r16) * KP + kq * 32 + quad * 8];
            acc[c] = __builtin_amdgcn_mfma_f32_16x16x32_bf16(a, b, acc[c],
                                                             0, 0, 0);
        }
    }
    // D: col = lane&15, row = quad*4 + reg (m89-verified)
#pragma unroll
    for (int c = 0; c < CCH; ++c) {
#pragma unroll
        for (int r = 0; r < 4; ++r) {
            int node = node0 + wv * 16 + quad * 4 + r;
            if (node < N)
                out[(size_t)node * M + c * 16 + r16] = f2bf(acc[c][r]);
        }
    }
}

// CSR aggregate, 64-wide bf16 rows (128 B). Wave per node: 8 slots x 8
// uint4-lanes, unroll x2 => 16 rows in flight. fp32 accumulate, bf16 out.
__global__ __launch_bounds__(256) void agg64_kernel(
    const ushort* __restrict__ h, const int2* __restrict__ edges,
    const int* __restrict__ offs, const float* __restrict__ dinv,
    ushort* __restrict__ out, int N) {
    const int wave = threadIdx.x >> 6, lane = threadIdx.x & 63;
    const int node = blockIdx.x * 4 + wave;
    if (node >= N) return;
    const int slot = lane >> 3;  // 0..7
    const int q = lane & 7;      // uint4 index within the 128 B row
    const uint4* __restrict__ h4 = (const uint4*)h;
    const int start = offs[node], end = offs[node + 1];
    float acc[8] = {};
    int j = start + slot;
    for (; j + 8 < end; j += 16) {
        int2 e0 = edges[j];
        int2 e1 = edges[j + 8];
        uint4 u0 = h4[(size_t)e0.x * 8 + q];
        uint4 u1 = h4[(size_t)e1.x * 8 + q];
        float n0 = __int_as_float(e0.y), n1 = __int_as_float(e1.y);
        acc[0] += bf_lo(u0.x) * n0 + bf_lo(u1.x) * n1;
        acc[1] += bf_hi(u0.x) * n0 + bf_hi(u1.x) * n1;
        acc[2] += bf_lo(u0.y) * n0 + bf_lo(u1.y) * n1;
        acc[3] += bf_hi(u0.y) * n0 + bf_hi(u1.y) * n1;
        acc[4] += bf_lo(u0.z) * n0 + bf_lo(u1.z) * n1;
        acc[5] += bf_hi(u0.z) * n0 + bf_hi(u1.z) * n1;
        acc[6] += bf_lo(u0.w) * n0 + bf_lo(u1.w) * n1;
        acc[7] += bf_hi(u0.w) * n0 + bf_hi(u1.w) * n1;
    }
    if (j < end) {
        int2 e0 = edges[j];
        uint4 u0 = h4[(size_t)e0.x * 8 + q];
        float n0 = __int_as_float(e0.y);
        acc[0] += bf_lo(u0.x) * n0; acc[1] += bf_hi(u0.x) * n0;
        acc[2] += bf_lo(u0.y) * n0; acc[3] += bf_hi(u0.y) * n0;
        acc[4] += bf_lo(u0.z) * n0; acc[5] += bf_hi(u0.z) * n0;
        acc[6] += bf_lo(u0.w) * n0; acc[7] += bf_hi(u0.w) * n0;
    }
#pragma unroll
    for (int k = 0; k < 8; ++k) {
        acc[k] += __shfl_xor(acc[k], 8);
        acc[k] += __shfl_xor(acc[k], 16);
        acc[k] += __shfl_xor(acc[k], 32);
    }
    if (slot == 0) {
        float di = dinv[node];
        float sc = di * di;
        uint4 hv = h4[(size_t)node * 8 + q];
        uint4 o;
        o.x = pack2bf(acc[0] + bf_lo(hv.x) * sc, acc[1] + bf_hi(hv.x) * sc);
        o.y = pack2bf(acc[2] + bf_lo(hv.y) * sc, acc[3] + bf_hi(hv.y) * sc);
        o.z = pack2bf(acc[4] + bf_lo(hv.z) * sc, acc[5] + bf_hi(hv.z) * sc);
        o.w = pack2bf(acc[6] + bf_lo(hv.w) * sc, acc[7] + bf_hi(hv.w) * sc);
        ((uint4*)out)[(size_t)node * 8 + q] = o;
    }
}

// CSR aggregate, 32-wide bf16 rows (64 B), final layer. Wave per node:
// 16 slots x 4 lanes. Fuses self-loop, +b3, fp32 d_out, spread mean buckets.
__global__ __launch_bounds__(256) void agg32_final_kernel(
    const ushort* __restrict__ h, const int2* __restrict__ edges,
    const int* __restrict__ offs, const float* __restrict__ dinv,
    const float* __restrict__ b3, float* __restrict__ out,
    float* __restrict__ mean_acc, int N) {
    __shared__ float ssum[32];
    if (threadIdx.x < 32) ssum[threadIdx.x] = 0.0f;
    __syncthreads();
    const int wave = threadIdx.x >> 6, lane = threadIdx.x & 63;
    const int node = blockIdx.x * 4 + wave;
    const int slot = lane >> 2;  // 0..15
    const int q = lane & 3;      // uint4 index within the 64 B row
    const uint4* __restrict__ h4 = (const uint4*)h;
    float acc[8] = {};
    if (node < N) {
        const int start = offs[node], end = offs[node + 1];
        for (int j = start + slot; j < end; j += 16) {
            int2 e0 = edges[j];
            uint4 u0 = h4[(size_t)e0.x * 4 + q];
            float n0 = __int_as_float(e0.y);
            acc[0] += bf_lo(u0.x) * n0; acc[1] += bf_hi(u0.x) * n0;
            acc[2] += bf_lo(u0.y) * n0; acc[3] += bf_hi(u0.y) * n0;
            acc[4] += bf_lo(u0.z) * n0; acc[5] += bf_hi(u0.z) * n0;
            acc[6] += bf_lo(u0.w) * n0; acc[7] += bf_hi(u0.w) * n0;
        }
    }
#pragma unroll
    for (int k = 0; k < 8; ++k) {
        acc[k] += __shfl_xor(acc[k], 4);
        acc[k] += __shfl_xor(acc[k], 8);
        acc[k] += __shfl_xor(acc[k], 16);
        acc[k] += __shfl_xor(acc[k], 32);
    }
    if (node < N && slot == 0) {
        float di = dinv[node];
        float sc = di * di;
        uint4 hv = h4[(size_t)node * 4 + q];
        const float4* b34 = (const float4*)b3;
        float4 bA = b34[q * 2], bB = b34[q * 2 + 1];
        float4 o0, o1;
        o0.x = acc[0] + bf_lo(hv.x) * sc + bA.x;
        o0.y = acc[1] + bf_hi(hv.x) * sc + bA.y;
        o0.z = acc[2] + bf_lo(hv.y) * sc + bA.z;
        o0.w = acc[3] + bf_hi(hv.y) * sc + bA.w;
        o1.x = acc[4] + bf_lo(hv.z) * sc + bB.x;
        o1.y = acc[5] + bf_hi(hv.z) * sc + bB.y;
        o1.z = acc[6] + bf_lo(hv.w) * sc + bB.z;
        o1.w = acc[7] + bf_hi(hv.w) * sc + bB.w;
        ((float4*)out)[(size_t)node * 8 + q * 2] = o0;
        ((float4*)out)[(size_t)node * 8 + q * 2 + 1] = o1;
        int fb = q * 8;
        atomicAdd(&ssum[fb + 0], o0.x); atomicAdd(&ssum[fb + 1], o0.y);
        atomicAdd(&ssum[fb + 2], o0.z); atomicAdd(&ssum[fb + 3], o0.w);
        atomicAdd(&ssum[fb + 4], o1.x); atomicAdd(&ssum[fb + 5], o1.y);
        atomicAdd(&ssum[fb + 6], o1.z); atomicAdd(&ssum[fb + 7], o1.w);
    }
    __syncthreads();
    if (threadIdx.x < 32) {
        // 128 spread buckets: same-address contention 25000 -> ~195
        int bucket = blockIdx.x & 127;
        atomicAdd(&mean_acc[bucket * 32 + threadIdx.x], ssum[threadIdx.x]);
    }
}

__global__ void write_mean_kernel(const float* __restrict__ mean_acc,
                                  float* __restrict__ out_tail, float invN) {
    int f = threadIdx.x;
    if (f < 32) {
        float s = 0.0f;
        for (int b = 0; b < 128; ++b) s += mean_acc[b * 32 + f];
        out_tail[f] = s * invN;
    }
}

extern "C" void kernel_launch(void* const* d_in, const int* in_sizes, int n_in,
                              void* d_out, int out_size, void* d_ws,
                              size_t ws_size, hipStream_t stream) {
    const float* x  = (const float*)d_in[0];
    const int*   ei = (const int*)d_in[1];
    const float* ew = (const float*)d_in[2];
    const float* W1 = (const float*)d_in[3];
    const float* b1 = (const float*)d_in[4];
    const float* W2 = (const float*)d_in[5];
    const float* b2 = (const float*)d_in[6];
    const float* W3 = (const float*)d_in[7];
    const float* b3 = (const float*)d_in[8];

    const int N = in_sizes[0] / 128;
    const int E = in_sizes[1] / 2;
    const int* src = ei;
    const int* dst = ei + E;

    const int NB = (N + 511) >> 9;          // coarse buckets (<= 256)
    const int EPB = (E + G - 1) / G;        // edges per pass-A/B block

    float* out = (float*)d_out;
    char* wsp = (char*)d_ws;
    auto carve = [&](size_t bytes) {
        char* p = wsp;
        wsp += (bytes + 255) & ~(size_t)255;
        return p;
    };
    float*  dinv       = (float*)carve((size_t)N * 4);
    int*    offs       = (int*)carve((size_t)(N + 1) * 4);
    int*    bucketBase = (int*)carve((MAXB + 1) * 4);
    int*    histG      = (int*)carve((size_t)MAXB * G * 4);
    int*    blockOffs  = (int*)carve((size_t)MAXB * G * 4);
    int2*   tmp        = (int2*)carve((size_t)E * 8);
    int2*   edges      = (int2*)carve((size_t)E * 8);
    ushort* hA         = (ushort*)carve((size_t)N * 64 * 2);
    ushort* hB         = (ushort*)carve((size_t)N * 64 * 2);
    ushort* W1T        = (ushort*)carve(128 * 64 * 2);
    ushort* W2T        = (ushort*)carve(64 * 64 * 2);
    ushort* W3T        = (ushort*)carve(64 * 32 * 2);
    float*  mean       = (float*)carve(128 * 32 * 4);

    const int nb_a = (N + 3) / 4;   // wave-per-node kernels: 4 nodes/block
    const int nb_g = (N + 63) / 64; // MFMA gemm: 64 nodes/block

    hipMemsetAsync(mean, 0, 128 * 32 * sizeof(float), stream);

    // ---- CSR build: LDS histograms -> scans -> bucket scatter -> fine sort
    //      (fine pass also emits offs and dinv). Zero global atomics. ----
    passA_hist_kernel<<<G, 1024, 0, stream>>>(dst, histG, E, EPB);
    bucket_scan_kernel<<<1, 256, 0, stream>>>(histG, bucketBase, NB, E);
    block_offs_kernel<<<NB, G, 0, stream>>>(histG, bucketBase, blockOffs);
    passB_scatter_kernel<<<G, 1024, 0, stream>>>(src, dst, ew, blockOffs, tmp,
                                                 E, EPB, NB);
    fine_kernel<<<NB, 512, 0, stream>>>(tmp, bucketBase, offs, edges, dinv, N,
                                        E, NB);
    norm_kernel<<<nb_a, 256, 0, stream>>>(edges, offs, dinv, N);

    // ---- W transposes to bf16 (tiny, once per call) ----
    wt_kernel<<<(128 * 64 + 255) / 256, 256, 0, stream>>>(W1, W1T, 128, 64);
    wt_kernel<<<(64 * 64 + 255) / 256, 256, 0, stream>>>(W2, W2T, 64, 64);
    wt_kernel<<<(64 * 32 + 255) / 256, 256, 0, stream>>>(W3, W3T, 64, 32);

    // ---- layer 1: hA = bf16(x @ W1); hB = A hA ----
    gemm_mfma_kernel<128, 64, false, false, false>
        <<<nb_g, 256, 0, stream>>>(x, W1T, nullptr, hA, N);
    agg64_kernel<<<nb_a, 256, 0, stream>>>(hA, edges, offs, dinv, hB, N);

    // ---- layer 2: hA = bf16(relu(hB + b1) @ W2); hB = A hA ----
    gemm_mfma_kernel<64, 64, true, true, true>
        <<<nb_g, 256, 0, stream>>>(hB, W2T, b1, hA, N);
    agg64_kernel<<<nb_a, 256, 0, stream>>>(hA, edges, offs, dinv, hB, N);

    // ---- layer 3: hA = bf16(relu(hB + b2) @ W3); out = A hA + b3; mean ----
    gemm_mfma_kernel<64, 32, true, true, true>
        <<<nb_g, 256, 0, stream>>>(hB, W3T, b2, hA, N);
    agg32_final_kernel<<<nb_a, 256, 0, stream>>>(hA, edges, offs, dinv, b3,
                                                 out, mean, N);

    // ---- epilogue: fold mean buckets ----
    write_mean_kernel<<<1, 32, 0, stream>>>(mean, out + (size_t)N * 32,
                                            1.0f / (float)N);
}